// Round 12
// baseline (1110.026 us; speedup 1.0000x reference)
//
#include <hip/hip_runtime.h>

// G4GCN: 4-layer linear bipartite GNN (clauses <-> variables), feature dim 2.
//
// Round-11 lesson: LDS-staged localsort fixed build write-amp (total 999us).
// Remaining: c_layer (3x88us, serial srcs->gather chain), v-chunks (~88us/
// layer across 4 dispatches + acc array traffic), build (~300us).
// Round-12:
//  - v_layer_m: ONE kernel per layer; in-kernel #pragma-unroll loop over the
//    4 yc chunk-windows with REGISTER accumulation (no acc array, rp read
//    once as uint4, one shfl-reduce). Guard: FETCH >=300MB means the L2
//    window discipline broke -> revert to split passes.
//  - unroll-2 gather loops on both sides: two independent y gathers in
//    flight per lane (halves the latency chain).
// Build (two-level partition + LDS-staged merged localsort) unchanged.

#define GAB 256    // blocks for build hist/scatter passes
#define BB  1024   // threads for build hist/scatter passes
#define CAPE 26624 // LDS staging capacity (entries) per super-bucket (104KB)

static inline int cdiv_h(long long a, long long b) { return (int)((a + b - 1) / b); }

__device__ inline float bf_lo(unsigned u) { return __uint_as_float(u << 16); }
__device__ inline float bf_hi(unsigned u) { return __uint_as_float(u & 0xffff0000u); }
__device__ inline unsigned packy(float a, float b) {
    unsigned ua = __float_as_uint(a), ub = __float_as_uint(b);
    ua = (ua + 0x7fffu + ((ua >> 16) & 1u)) >> 16;
    ub = (ub + 0x7fffu + ((ub >> 16) & 1u)) & 0xffff0000u;
    return ua | ub;
}

// ---------------- build ----------------

// one pass over an edge list: histogram BOTH views (v by trg>>sv, c by src>>sc)
__global__ __launch_bounds__(BB) void hist_both(
    const int* __restrict__ keyV, const int* __restrict__ keyC,
    int e, int chunk, int sv, int sc, int nbv, int nbc,
    unsigned* __restrict__ histV, unsigned* __restrict__ histC) {
    extern __shared__ unsigned h[];  // nbv*4 + nbc*4 (4-way replicated)
    unsigned* hv = h;
    unsigned* hc = h + nbv * 4;
    int blk = blockIdx.x, tid = threadIdx.x;
    for (int i = tid; i < (nbv + nbc) * 4; i += blockDim.x) h[i] = 0u;
    __syncthreads();
    int s = blk * chunk, epos = min(e, s + chunk);
    int r = tid & 3;
    for (int i = s + tid; i < epos; i += blockDim.x) {
        atomicAdd(&hv[(((unsigned)(keyV[i] >> sv)) << 2) | r], 1u);
        atomicAdd(&hc[(((unsigned)(keyC[i] >> sc)) << 2) | r], 1u);
    }
    __syncthreads();
    for (int i = tid; i < nbv; i += blockDim.x)
        histV[(size_t)i * GAB + blk] = hv[4 * i] + hv[4 * i + 1] + hv[4 * i + 2] + hv[4 * i + 3];
    for (int i = tid; i < nbc; i += blockDim.x)
        histC[(size_t)i * GAB + blk] = hc[4 * i] + hc[4 * i + 1] + hc[4 * i + 2] + hc[4 * i + 3];
}

__global__ void rowscan256(const unsigned* __restrict__ hist, unsigned* __restrict__ rowscan,
                           unsigned* __restrict__ row_total) {
    __shared__ unsigned ts[256];
    int b = blockIdx.x, t = threadIdx.x;
    unsigned v0 = hist[(size_t)b * GAB + t];
    ts[t] = v0;
    __syncthreads();
    for (int off = 1; off < 256; off <<= 1) {
        unsigned v = (t >= off) ? ts[t - off] : 0u;
        __syncthreads();
        ts[t] += v;
        __syncthreads();
    }
    rowscan[(size_t)b * GAB + t] = ts[t] - v0;
    if (t == 255) row_total[b] = ts[255];
}

// exclusive scan of (totP+totN) -> base[0..nb]; baseNeg[i] = base[i] + totP[i]
__global__ void basescan2(const unsigned* __restrict__ totP, const unsigned* __restrict__ totN,
                          unsigned* __restrict__ base, unsigned* __restrict__ baseNeg, int nb) {
    __shared__ unsigned a[2048];
    __shared__ unsigned ts[1024];
    int t = threadIdx.x;
    a[t] = (t < nb) ? (totP[t] + totN[t]) : 0u;
    a[t + 1024] = (t + 1024 < nb) ? (totP[t + 1024] + totN[t + 1024]) : 0u;
    __syncthreads();
    unsigned a0 = a[2 * t], a1 = a[2 * t + 1];
    unsigned sum = a0 + a1;
    ts[t] = sum;
    __syncthreads();
    for (int off = 1; off < 1024; off <<= 1) {
        unsigned v = (t >= off) ? ts[t - off] : 0u;
        __syncthreads();
        ts[t] += v;
        __syncthreads();
    }
    unsigned b0 = ts[t] - sum;
    if (2 * t <= nb) base[2 * t] = b0;
    if (2 * t + 1 <= nb) base[2 * t + 1] = b0 + a0;
    if (2 * t < nb) baseNeg[2 * t] = b0 + totP[2 * t];
    if (2 * t + 1 < nb) baseNeg[2 * t + 1] = b0 + a0 + totP[2 * t + 1];
}

// coarse scatter: bucket by key>>kshift; entry = (pay << kshift) | (key & mask)
__global__ __launch_bounds__(BB) void scatter_sb(
    const int* __restrict__ key, const int* __restrict__ pay,
    int e, int chunk, int kshift, int nb,
    const unsigned* __restrict__ rowscan, const unsigned* __restrict__ base,
    unsigned* __restrict__ out) {
    extern __shared__ unsigned cur[];
    int blk = blockIdx.x, tid = threadIdx.x;
    for (int i = tid; i < nb; i += blockDim.x)
        cur[i] = base[i] + rowscan[(size_t)i * GAB + blk];
    __syncthreads();
    int s = blk * chunk, epos = min(e, s + chunk);
    unsigned mask = (1u << kshift) - 1u;
    for (int i = s + tid; i < epos; i += blockDim.x) {
        int k = key[i];
        int b = k >> kshift;
        unsigned p = atomicAdd(&cur[b], 1u);
        out[p] = ((unsigned)pay[i] << kshift) | ((unsigned)k & mask);
    }
}

// merged v-view localsort, LDS-staged: SB = 1024 vars, [pos|neg] segments.
// entry = (c<<10)|(v&1023); key = (v&1023)<<2 | chunk(c). srcs = (pol<<31)|c.
__global__ __launch_bounds__(1024) void localsort_v_m(
    const unsigned* __restrict__ ent, const unsigned* __restrict__ base,
    const unsigned* __restrict__ baseNeg, int nsb, int nv, int cs,
    unsigned* __restrict__ srcs, unsigned* __restrict__ rp, unsigned* __restrict__ cnts) {
    __shared__ unsigned h[4096];
    __shared__ unsigned ts[1024];
    __shared__ unsigned buf[CAPE];
    int s = blockIdx.x, t = threadIdx.x;
    unsigned sb = base[s], pe = baseNeg[s], se = base[s + 1];
    bool fits = (se - sb) <= (unsigned)CAPE;
    for (int k = 0; k < 4; ++k) h[t * 4 + k] = 0u;
    __syncthreads();
    for (unsigned i = sb + t; i < pe; i += 1024) {  // count pos
        unsigned u = ent[i];
        atomicAdd(&h[((u & 1023u) << 2) | ((u >> 10) >> cs)], 1u);
    }
    __syncthreads();
    unsigned pc[4];
    for (int k = 0; k < 4; ++k) pc[k] = h[t * 4 + k];
    __syncthreads();
    for (unsigned i = pe + t; i < se; i += 1024) {  // count neg on top
        unsigned u = ent[i];
        atomicAdd(&h[((u & 1023u) << 2) | ((u >> 10) >> cs)], 1u);
    }
    __syncthreads();
    unsigned v0[4];
    unsigned sum = 0;
    for (int k = 0; k < 4; ++k) { v0[k] = h[t * 4 + k]; sum += v0[k]; }
    ts[t] = sum;
    __syncthreads();
    for (int off = 1; off < 1024; off <<= 1) {
        unsigned x = (t >= off) ? ts[t - off] : 0u;
        __syncthreads();
        ts[t] += x;
        __syncthreads();
    }
    unsigned ex = ts[t] - sum;
    unsigned hx[4];
    for (int k = 0; k < 4; ++k) { hx[k] = ex; ex += v0[k]; }
    int node = s * 1024 + t;
    if (node < nv) {
        for (int ch = 0; ch < 4; ++ch) rp[(size_t)node * 4 + ch] = sb + hx[ch];
        unsigned cp = pc[0] + pc[1] + pc[2] + pc[3];
        unsigned tot = v0[0] + v0[1] + v0[2] + v0[3];
        cnts[node] = (cp << 16) | (tot - cp);
    }
    if (s == nsb - 1 && t == 0) rp[(size_t)nv * 4] = se;
    for (int k = 0; k < 4; ++k) h[t * 4 + k] = hx[k];
    __syncthreads();
    if (fits) {
        for (unsigned i = sb + t; i < pe; i += 1024) {
            unsigned u = ent[i];
            unsigned p = atomicAdd(&h[((u & 1023u) << 2) | ((u >> 10) >> cs)], 1u);
            buf[p] = u >> 10;
        }
        for (unsigned i = pe + t; i < se; i += 1024) {
            unsigned u = ent[i];
            unsigned p = atomicAdd(&h[((u & 1023u) << 2) | ((u >> 10) >> cs)], 1u);
            buf[p] = 0x80000000u | (u >> 10);
        }
        __syncthreads();
        unsigned n = se - sb;
        for (unsigned i = t; i < n; i += 1024) srcs[sb + i] = buf[i];
    } else {  // overflow fallback: direct global scatter (correct, slower)
        for (unsigned i = sb + t; i < pe; i += 1024) {
            unsigned u = ent[i];
            unsigned p = atomicAdd(&h[((u & 1023u) << 2) | ((u >> 10) >> cs)], 1u);
            srcs[sb + p] = u >> 10;
        }
        for (unsigned i = pe + t; i < se; i += 1024) {
            unsigned u = ent[i];
            unsigned p = atomicAdd(&h[((u & 1023u) << 2) | ((u >> 10) >> cs)], 1u);
            srcs[sb + p] = 0x80000000u | (u >> 10);
        }
    }
}

// merged c-view localsort, LDS-staged: SB = 4096 clauses. entry = (v<<12)|(c&4095)
__global__ __launch_bounds__(1024) void localsort_c_m(
    const unsigned* __restrict__ ent, const unsigned* __restrict__ base,
    const unsigned* __restrict__ baseNeg, int nsb, int nc,
    unsigned* __restrict__ srcs, unsigned* __restrict__ rp, unsigned* __restrict__ cnts) {
    __shared__ unsigned h[4096];
    __shared__ unsigned ts[1024];
    __shared__ unsigned buf[CAPE];
    int s = blockIdx.x, t = threadIdx.x;
    unsigned sb = base[s], pe = baseNeg[s], se = base[s + 1];
    bool fits = (se - sb) <= (unsigned)CAPE;
    for (int k = 0; k < 4; ++k) h[t * 4 + k] = 0u;
    __syncthreads();
    for (unsigned i = sb + t; i < pe; i += 1024)
        atomicAdd(&h[ent[i] & 4095u], 1u);
    __syncthreads();
    unsigned pc[4];
    for (int k = 0; k < 4; ++k) pc[k] = h[t * 4 + k];
    __syncthreads();
    for (unsigned i = pe + t; i < se; i += 1024)
        atomicAdd(&h[ent[i] & 4095u], 1u);
    __syncthreads();
    unsigned v0[4];
    unsigned sum = 0;
    for (int k = 0; k < 4; ++k) { v0[k] = h[t * 4 + k]; sum += v0[k]; }
    ts[t] = sum;
    __syncthreads();
    for (int off = 1; off < 1024; off <<= 1) {
        unsigned x = (t >= off) ? ts[t - off] : 0u;
        __syncthreads();
        ts[t] += x;
        __syncthreads();
    }
    unsigned ex = ts[t] - sum;
    unsigned hx[4];
    for (int k = 0; k < 4; ++k) { hx[k] = ex; ex += v0[k]; }
    int node0 = s * 4096 + t * 4;
    for (int k = 0; k < 4; ++k) {
        int node = node0 + k;
        if (node < nc) {
            rp[node] = sb + hx[k];
            cnts[node] = (pc[k] << 16) | (v0[k] - pc[k]);
        }
    }
    if (s == nsb - 1 && t == 0) rp[nc] = se;
    for (int k = 0; k < 4; ++k) h[t * 4 + k] = hx[k];
    __syncthreads();
    if (fits) {
        for (unsigned i = sb + t; i < pe; i += 1024) {
            unsigned u = ent[i];
            unsigned p = atomicAdd(&h[u & 4095u], 1u);
            buf[p] = u >> 12;
        }
        for (unsigned i = pe + t; i < se; i += 1024) {
            unsigned u = ent[i];
            unsigned p = atomicAdd(&h[u & 4095u], 1u);
            buf[p] = 0x80000000u | (u >> 12);
        }
        __syncthreads();
        unsigned n = se - sb;
        for (unsigned i = t; i < n; i += 1024) srcs[sb + i] = buf[i];
    } else {
        for (unsigned i = sb + t; i < pe; i += 1024) {
            unsigned u = ent[i];
            unsigned p = atomicAdd(&h[u & 4095u], 1u);
            srcs[sb + p] = u >> 12;
        }
        for (unsigned i = pe + t; i < se; i += 1024) {
            unsigned u = ent[i];
            unsigned p = atomicAdd(&h[u & 4095u], 1u);
            srcs[sb + p] = 0x80000000u | (u >> 12);
        }
    }
}

// ---------------- node init ----------------

__global__ void init_c_kernel(const float* __restrict__ x, const float* __restrict__ deg,
                              const float* __restrict__ W0, const float* __restrict__ b0,
                              float2* __restrict__ xc, unsigned* __restrict__ yc, int n) {
    int i = blockIdx.x * blockDim.x + threadIdx.x;
    if (i >= n) return;
    float xi = x[i];
    float2 o = make_float2(fmaf(xi, W0[0], b0[0]), fmaf(xi, W0[1], b0[1]));
    xc[i] = o;
    float d = deg[i];
    float inv = (d > 0.f) ? rsqrtf(d) : 0.f;
    yc[i] = packy(inv * o.x, inv * o.y);
}

__global__ void init_v_kernel(const float* __restrict__ x, const float* __restrict__ deg,
                              const float* __restrict__ W0, const float* __restrict__ b0,
                              float2* __restrict__ xv, unsigned* __restrict__ yv, int n) {
    int i = blockIdx.x * blockDim.x + threadIdx.x;
    if (i >= n) return;
    float xi = x[i];
    float2 o = make_float2(fmaf(xi, W0[0], b0[0]), fmaf(xi, W0[1], b0[1]));
    xv[i] = o;
    float d = deg[i];
    float inv = (d > 0.f) ? rsqrtf(d) : 0.f;
    yv[i] = packy(inv * o.x, inv * o.y);
}

// ---------------- per-layer kernels ----------------

// unified v layer: in-kernel loop over 4 yc chunk-windows, register accum,
// unroll-2 gathers, fused 6->2 update. 4 lanes per node.
__global__ __launch_bounds__(256) void v_layer_k(
    const unsigned* __restrict__ rp, const unsigned* __restrict__ srcs,
    const unsigned* __restrict__ yc, const unsigned* __restrict__ cnts,
    float2* __restrict__ xv, const float* __restrict__ deg_v,
    const float* __restrict__ W, const float* __restrict__ bias,
    unsigned* __restrict__ yv_out, int nv, int writeY) {
    int gt = blockIdx.x * blockDim.x + threadIdx.x;
    int i = gt >> 2, q = gt & 3;
    if (i >= nv) return;
    uint4 rq = *reinterpret_cast<const uint4*>(rp + (size_t)i * 4);
    unsigned e3 = rp[(size_t)(i + 1) * 4];
    float ax = 0.f, ay = 0.f, bx = 0.f, by = 0.f;
    unsigned segs[5] = { rq.x, rq.y, rq.z, rq.w, e3 };
    #pragma unroll
    for (int k = 0; k < 4; ++k) {
        unsigned s0 = segs[k], e0 = segs[k + 1];
        unsigned j = s0 + q;
        for (; j + 4 < e0; j += 8) {
            unsigned u0 = srcs[j], u1 = srcs[j + 4];
            unsigned y0 = yc[u0 & 0x7fffffffu], y1 = yc[u1 & 0x7fffffffu];
            float t0 = (u0 & 0x80000000u) ? 0.f : 1.f;
            float t1 = (u1 & 0x80000000u) ? 0.f : 1.f;
            float l0 = bf_lo(y0), h0 = bf_hi(y0);
            float l1 = bf_lo(y1), h1 = bf_hi(y1);
            ax = fmaf(t0, l0, ax); ay = fmaf(t0, h0, ay);
            bx = fmaf(1.f - t0, l0, bx); by = fmaf(1.f - t0, h0, by);
            ax = fmaf(t1, l1, ax); ay = fmaf(t1, h1, ay);
            bx = fmaf(1.f - t1, l1, bx); by = fmaf(1.f - t1, h1, by);
        }
        if (j < e0) {
            unsigned u = srcs[j];
            unsigned yw = yc[u & 0x7fffffffu];
            float tp = (u & 0x80000000u) ? 0.f : 1.f;
            float lo = bf_lo(yw), hi = bf_hi(yw);
            ax = fmaf(tp, lo, ax); ay = fmaf(tp, hi, ay);
            bx = fmaf(1.f - tp, lo, bx); by = fmaf(1.f - tp, hi, by);
        }
    }
    for (int m = 1; m < 4; m <<= 1) {
        ax += __shfl_xor(ax, m, 4);
        ay += __shfl_xor(ay, m, 4);
        bx += __shfl_xor(bx, m, 4);
        by += __shfl_xor(by, m, 4);
    }
    if (q == 0) {
        unsigned ct = cnts[i];
        float cp = (float)(ct >> 16), cn = (float)(ct & 0xffffu);
        float2 xi = xv[i];
        float dv = deg_v[i];
        float iv = (dv > 0.f) ? rsqrtf(dv) : 0.f;
        float m0 = fmaf(iv, ax, cp * xi.x);
        float m1 = fmaf(iv, ay, cp * xi.y);
        float m2 = fmaf(iv, bx, cn * xi.x);
        float m3 = fmaf(iv, by, cn * xi.y);
        float o0 = bias[0] + m0 * W[0] + m1 * W[2] + m2 * W[4] + m3 * W[6] + xi.x * W[8] + xi.y * W[10];
        float o1 = bias[1] + m0 * W[1] + m1 * W[3] + m2 * W[5] + m3 * W[7] + xi.x * W[9] + xi.y * W[11];
        xv[i] = make_float2(o0, o1);
        if (writeY) yv_out[i] = packy(iv * o0, iv * o1);
    }
}

// clause layer: merged row, unroll-2 gathers, fused update; optional xc store
__global__ __launch_bounds__(256) void c_layer_m(
    const unsigned* __restrict__ rp, const unsigned* __restrict__ srcs,
    const unsigned* __restrict__ cnts, const unsigned* __restrict__ yv,
    float2* __restrict__ xc, const float* __restrict__ deg_c,
    unsigned* __restrict__ yc, const float* __restrict__ W,
    const float* __restrict__ bias, int nc, int writeX) {
    int gt = blockIdx.x * blockDim.x + threadIdx.x;
    int i = gt >> 2, q = gt & 3;
    if (i >= nc) return;
    unsigned s0 = rp[i], e0 = rp[i + 1];
    float ax = 0.f, ay = 0.f, bx = 0.f, by = 0.f;
    unsigned j = s0 + q;
    for (; j + 4 < e0; j += 8) {
        unsigned u0 = srcs[j], u1 = srcs[j + 4];
        unsigned y0 = yv[u0 & 0x7fffffffu], y1 = yv[u1 & 0x7fffffffu];
        float t0 = (u0 & 0x80000000u) ? 0.f : 1.f;
        float t1 = (u1 & 0x80000000u) ? 0.f : 1.f;
        float l0 = bf_lo(y0), h0 = bf_hi(y0);
        float l1 = bf_lo(y1), h1 = bf_hi(y1);
        ax = fmaf(t0, l0, ax); ay = fmaf(t0, h0, ay);
        bx = fmaf(1.f - t0, l0, bx); by = fmaf(1.f - t0, h0, by);
        ax = fmaf(t1, l1, ax); ay = fmaf(t1, h1, ay);
        bx = fmaf(1.f - t1, l1, bx); by = fmaf(1.f - t1, h1, by);
    }
    if (j < e0) {
        unsigned u = srcs[j];
        unsigned yw = yv[u & 0x7fffffffu];
        float tp = (u & 0x80000000u) ? 0.f : 1.f;
        float lo = bf_lo(yw), hi = bf_hi(yw);
        ax = fmaf(tp, lo, ax); ay = fmaf(tp, hi, ay);
        bx = fmaf(1.f - tp, lo, bx); by = fmaf(1.f - tp, hi, by);
    }
    for (int m = 1; m < 4; m <<= 1) {
        ax += __shfl_xor(ax, m, 4);
        ay += __shfl_xor(ay, m, 4);
        bx += __shfl_xor(bx, m, 4);
        by += __shfl_xor(by, m, 4);
    }
    if (q == 0) {
        unsigned ct = cnts[i];
        float cp = (float)(ct >> 16), cn = (float)(ct & 0xffffu);
        float2 xi = xc[i];
        float dc = deg_c[i];
        float ic = (dc > 0.f) ? rsqrtf(dc) : 0.f;
        float m0 = fmaf(ic, ax, cp * xi.x);
        float m1 = fmaf(ic, ay, cp * xi.y);
        float m2 = fmaf(ic, bx, cn * xi.x);
        float m3 = fmaf(ic, by, cn * xi.y);
        float o0 = bias[0] + m0 * W[0] + m1 * W[2] + m2 * W[4] + m3 * W[6] + xi.x * W[8] + xi.y * W[10];
        float o1 = bias[1] + m0 * W[1] + m1 * W[3] + m2 * W[5] + m3 * W[7] + xi.x * W[9] + xi.y * W[11];
        if (writeX) xc[i] = make_float2(o0, o1);
        yc[i] = packy(ic * o0, ic * o1);
    }
}

// ---------------- fallback: global-atomic path ----------------

__global__ void init_nodes(const float* __restrict__ x, const float* __restrict__ deg,
                           const float* __restrict__ W0, const float* __restrict__ b0,
                           float2* __restrict__ xf, float* __restrict__ inv, int n) {
    int i = blockIdx.x * blockDim.x + threadIdx.x;
    if (i >= n) return;
    float xi = x[i];
    xf[i] = make_float2(fmaf(xi, W0[0], b0[0]), fmaf(xi, W0[1], b0[1]));
    float d = deg[i];
    inv[i] = (d > 0.0f) ? (1.0f / sqrtf(d)) : 0.0f;
}

__global__ void count_edges(const int* __restrict__ src, const int* __restrict__ trg,
                            float* __restrict__ cnt_src, float* __restrict__ cnt_trg, int e) {
    int i = blockIdx.x * blockDim.x + threadIdx.x;
    if (i >= e) return;
    atomicAdd(&cnt_src[src[i]], 1.0f);
    atomicAdd(&cnt_trg[trg[i]], 1.0f);
}

__global__ void edge_pass(const int* __restrict__ src, const int* __restrict__ trg,
                          const float2* __restrict__ xc, const float2* __restrict__ xv,
                          const float* __restrict__ inv_c, const float* __restrict__ inv_v,
                          float2* __restrict__ Sv, float2* __restrict__ Sc, int e) {
    int i = blockIdx.x * blockDim.x + threadIdx.x;
    if (i >= e) return;
    int c = src[i];
    int v = trg[i];
    float ic = inv_c[c], iv = inv_v[v];
    float2 a = xc[c];
    float2 b = xv[v];
    atomicAdd(&Sv[v].x, a.x * ic);
    atomicAdd(&Sv[v].y, a.y * ic);
    atomicAdd(&Sc[c].x, b.x * iv);
    atomicAdd(&Sc[c].y, b.y * iv);
}

__global__ void node_update(float2* __restrict__ x, const float2* __restrict__ Sp,
                            const float2* __restrict__ Sn, const float* __restrict__ inv,
                            const float* __restrict__ cp, const float* __restrict__ cn,
                            const float* __restrict__ W, const float* __restrict__ b, int n) {
    int i = blockIdx.x * blockDim.x + threadIdx.x;
    if (i >= n) return;
    float2 xi = x[i];
    float ii = inv[i];
    float2 sp = Sp[i], sn = Sn[i];
    float cpi = cp[i], cni = cn[i];
    float m0 = fmaf(ii, sp.x, cpi * xi.x);
    float m1 = fmaf(ii, sp.y, cpi * xi.y);
    float m2 = fmaf(ii, sn.x, cni * xi.x);
    float m3 = fmaf(ii, sn.y, cni * xi.y);
    float o0 = b[0] + m0 * W[0] + m1 * W[2] + m2 * W[4] + m3 * W[6] + xi.x * W[8] + xi.y * W[10];
    float o1 = b[1] + m0 * W[1] + m1 * W[3] + m2 * W[5] + m3 * W[7] + xi.x * W[9] + xi.y * W[11];
    x[i] = make_float2(o0, o1);
}

// ---------------- launch ----------------

extern "C" void kernel_launch(void* const* d_in, const int* in_sizes, int n_in,
                              void* d_out, int out_size, void* d_ws, size_t ws_size,
                              hipStream_t stream) {
    const float* x_clause   = (const float*)d_in[0];
    const float* x_variable = (const float*)d_in[1];
    const float* deg_clause = (const float*)d_in[2];
    const float* deg_var    = (const float*)d_in[3];
    const int*   pos_src    = (const int*)d_in[4];
    const int*   pos_trg    = (const int*)d_in[5];
    const int*   neg_src    = (const int*)d_in[6];
    const int*   neg_trg    = (const int*)d_in[7];
    const float* W0c        = (const float*)d_in[8];
    const float* b0c        = (const float*)d_in[9];
    const float* W0v        = (const float*)d_in[10];
    const float* b0v        = (const float*)d_in[11];
    const float* Wc         = (const float*)d_in[12];
    const float* bc         = (const float*)d_in[13];
    const float* Wv         = (const float*)d_in[14];
    const float* bv         = (const float*)d_in[15];

    const int nc = in_sizes[0];
    const int nv = in_sizes[1];
    const int e  = in_sizes[4];
    const int B = 256;

    const int NSBV = cdiv_h(nv, 1024);   // v super-buckets (1024 vars each)
    const int NSBC = cdiv_h(nc, 4096);   // c super-buckets (4096 clauses each)
    const int maxnb = NSBV > NSBC ? NSBV : NSBC;
    const bool pack_ok = (nc <= (1 << 21)) && (nv <= (1 << 19)) &&
                         (NSBV <= 2040) && (NSBC <= 2040);

    int cs = 0;  // clause-chunk shift: 4 chunks cover nc
    while ((4LL << cs) < nc) cs++;

    // -------- tier-1 layout: persistent merged CSRs + build/layer overlay --------
    {
        size_t off = 0;
        auto alloc = [&](size_t bytes) {
            void* p = (char*)d_ws + off;
            off += (bytes + 255) & ~(size_t)255;
            return p;
        };
        unsigned* srcs_v = (unsigned*)alloc((size_t)2 * e * 4);          // (pol<<31)|c
        unsigned* srcs_c = (unsigned*)alloc((size_t)2 * e * 4);          // (pol<<31)|v
        unsigned* rp_v   = (unsigned*)alloc((size_t)4 * (nv + 1) * 4);   // node-major [node*4+chunk]
        unsigned* rp_c   = (unsigned*)alloc((size_t)(nc + 1) * 4);
        unsigned* cnts_v = (unsigned*)alloc((size_t)nv * 4);             // (cp<<16)|cn
        unsigned* cnts_c = (unsigned*)alloc((size_t)nc * 4);
        const size_t overlay = off;
        // build-time view
        unsigned* temp    = (unsigned*)alloc((size_t)2 * e * 4);
        unsigned* histVP  = (unsigned*)alloc((size_t)maxnb * GAB * 4);
        unsigned* histVN  = (unsigned*)alloc((size_t)maxnb * GAB * 4);
        unsigned* histCP  = (unsigned*)alloc((size_t)maxnb * GAB * 4);
        unsigned* histCN  = (unsigned*)alloc((size_t)maxnb * GAB * 4);
        unsigned* rsVP    = (unsigned*)alloc((size_t)maxnb * GAB * 4);
        unsigned* rsVN    = (unsigned*)alloc((size_t)maxnb * GAB * 4);
        unsigned* rsCP    = (unsigned*)alloc((size_t)maxnb * GAB * 4);
        unsigned* rsCN    = (unsigned*)alloc((size_t)maxnb * GAB * 4);
        unsigned* totVP   = (unsigned*)alloc((size_t)maxnb * 4);
        unsigned* totVN   = (unsigned*)alloc((size_t)maxnb * 4);
        unsigned* totCP   = (unsigned*)alloc((size_t)maxnb * 4);
        unsigned* totCN   = (unsigned*)alloc((size_t)maxnb * 4);
        unsigned* baseV   = (unsigned*)alloc((size_t)(NSBV + 1) * 4);
        unsigned* baseVN  = (unsigned*)alloc((size_t)(NSBV + 1) * 4);
        unsigned* baseC   = (unsigned*)alloc((size_t)(NSBC + 1) * 4);
        unsigned* baseCN  = (unsigned*)alloc((size_t)(NSBC + 1) * 4);
        const size_t build_end = off;
        // layer-time view (overlaps build scratch; inits run AFTER build)
        off = overlay;
        float2*   xc      = (float2*)alloc((size_t)nc * 8);
        unsigned* yc      = (unsigned*)alloc((size_t)nc * 4);
        unsigned* yvA     = (unsigned*)alloc((size_t)nv * 4);
        unsigned* yvB     = (unsigned*)alloc((size_t)nv * 4);
        const size_t layer_end = off;
        const size_t required = build_end > layer_end ? build_end : layer_end;

        if (required <= ws_size && pack_ok) {
            const int chunk = cdiv_h(e, GAB);
            // histograms: one pass per edge list computes BOTH views
            hist_both<<<GAB, BB, (size_t)(NSBV + NSBC) * 16, stream>>>(
                pos_trg, pos_src, e, chunk, 10, 12, NSBV, NSBC, histVP, histCP);
            hist_both<<<GAB, BB, (size_t)(NSBV + NSBC) * 16, stream>>>(
                neg_trg, neg_src, e, chunk, 10, 12, NSBV, NSBC, histVN, histCN);
            rowscan256<<<NSBV, B, 0, stream>>>(histVP, rsVP, totVP);
            rowscan256<<<NSBV, B, 0, stream>>>(histVN, rsVN, totVN);
            rowscan256<<<NSBC, B, 0, stream>>>(histCP, rsCP, totCP);
            rowscan256<<<NSBC, B, 0, stream>>>(histCN, rsCN, totCN);
            basescan2<<<1, 1024, 0, stream>>>(totVP, totVN, baseV, baseVN, NSBV);
            basescan2<<<1, 1024, 0, stream>>>(totCP, totCN, baseC, baseCN, NSBC);
            // V view: pos then neg into [pos|neg] SB segments, then LDS-staged localsort
            scatter_sb<<<GAB, BB, (size_t)NSBV * 4, stream>>>(pos_trg, pos_src, e, chunk,
                                                              10, NSBV, rsVP, baseV, temp);
            scatter_sb<<<GAB, BB, (size_t)NSBV * 4, stream>>>(neg_trg, neg_src, e, chunk,
                                                              10, NSBV, rsVN, baseVN, temp);
            localsort_v_m<<<NSBV, 1024, 0, stream>>>(temp, baseV, baseVN, NSBV, nv, cs,
                                                     srcs_v, rp_v, cnts_v);
            // C view
            scatter_sb<<<GAB, BB, (size_t)NSBC * 4, stream>>>(pos_src, pos_trg, e, chunk,
                                                              12, NSBC, rsCP, baseC, temp);
            scatter_sb<<<GAB, BB, (size_t)NSBC * 4, stream>>>(neg_src, neg_trg, e, chunk,
                                                              12, NSBC, rsCN, baseCN, temp);
            localsort_c_m<<<NSBC, 1024, 0, stream>>>(temp, baseC, baseCN, NSBC, nc,
                                                     srcs_c, rp_c, cnts_c);

            float2* xv = (float2*)d_out;  // updated in place each layer
            init_c_kernel<<<cdiv_h(nc, B), B, 0, stream>>>(x_clause, deg_clause, W0c, b0c, xc, yc, nc);
            init_v_kernel<<<cdiv_h(nv, B), B, 0, stream>>>(x_variable, deg_var, W0v, b0v, xv, yvA, nv);

            unsigned* ycur = yvA;  // yv of layer l
            unsigned* ynxt = yvB;  // yv of layer l+1
            for (int l = 0; l < 4; ++l) {
                v_layer_k<<<cdiv_h((long long)nv * 4, B), B, 0, stream>>>(
                    rp_v, srcs_v, yc, cnts_v, xv, deg_var,
                    Wv + l * 12, bv + l * 2, ynxt, nv, (l < 2) ? 1 : 0);
                if (l < 3) {
                    c_layer_m<<<cdiv_h((long long)nc * 4, B), B, 0, stream>>>(
                        rp_c, srcs_c, cnts_c, ycur, xc, deg_clause, yc,
                        Wc + l * 12, bc + l * 2, nc, (l < 2) ? 1 : 0);
                }
                unsigned* ty = ycur; ycur = ynxt; ynxt = ty;
            }
            return;
        }
    }

    // -------- fallback: global-atomic path --------
    char* p = (char*)d_ws;
    float2* Sv_pos = (float2*)p; p += (size_t)nv * sizeof(float2);
    float2* Sv_neg = (float2*)p; p += (size_t)nv * sizeof(float2);
    float2* Sc_pos = (float2*)p; p += (size_t)nc * sizeof(float2);
    float2* Sc_neg = (float2*)p; p += (size_t)nc * sizeof(float2);
    const size_t s_bytes = (size_t)(2 * nv + 2 * nc) * sizeof(float2);
    float2* xc2 = (float2*)p; p += (size_t)nc * sizeof(float2);
    float* inv_c = (float*)p; p += (size_t)nc * sizeof(float);
    float* inv_v = (float*)p; p += (size_t)nv * sizeof(float);
    float* cntc_pos = (float*)p; p += (size_t)nc * sizeof(float);
    float* cntc_neg = (float*)p; p += (size_t)nc * sizeof(float);
    float* cntv_pos = (float*)p; p += (size_t)nv * sizeof(float);
    float* cntv_neg = (float*)p; p += (size_t)nv * sizeof(float);
    const size_t cnt_bytes = (size_t)(2 * nc + 2 * nv) * sizeof(float);
    float2* xv = (float2*)d_out;

    hipMemsetAsync(Sv_pos, 0, s_bytes, stream);
    hipMemsetAsync(cntc_pos, 0, cnt_bytes, stream);
    init_nodes<<<cdiv_h(nc, B), B, 0, stream>>>(x_clause, deg_clause, W0c, b0c, xc2, inv_c, nc);
    init_nodes<<<cdiv_h(nv, B), B, 0, stream>>>(x_variable, deg_var, W0v, b0v, xv, inv_v, nv);
    count_edges<<<cdiv_h(e, B), B, 0, stream>>>(pos_src, pos_trg, cntc_pos, cntv_pos, e);
    count_edges<<<cdiv_h(e, B), B, 0, stream>>>(neg_src, neg_trg, cntc_neg, cntv_neg, e);
    for (int l = 0; l < 4; ++l) {
        edge_pass<<<cdiv_h(e, B), B, 0, stream>>>(pos_src, pos_trg, xc2, xv, inv_c, inv_v,
                                                  Sv_pos, Sc_pos, e);
        edge_pass<<<cdiv_h(e, B), B, 0, stream>>>(neg_src, neg_trg, xc2, xv, inv_c, inv_v,
                                                  Sv_neg, Sc_neg, e);
        node_update<<<cdiv_h(nv, B), B, 0, stream>>>(xv, Sv_pos, Sv_neg, inv_v,
                                                     cntv_pos, cntv_neg, Wv + l * 12, bv + l * 2, nv);
        node_update<<<cdiv_h(nc, B), B, 0, stream>>>(xc2, Sc_pos, Sc_neg, inv_c,
                                                     cntc_pos, cntc_neg, Wc + l * 12, bc + l * 2, nc);
        if (l < 3) hipMemsetAsync(Sv_pos, 0, s_bytes, stream);
    }
}

// Round 13
// 952.096 us; speedup vs baseline: 1.1659x; 1.1659x over previous
//
#include <hip/hip_runtime.h>

// G4GCN: 4-layer linear bipartite GNN (clauses <-> variables), feature dim 2.
//
// Round-12 lesson: fusing the 4 v-chunk passes into one kernel broke the L2
// window discipline (guard fired: FETCH 478MB vs ~60MB expected) — without
// the kernel-launch barrier, concurrent blocks sit in DIFFERENT yc windows
// and the 8MB yc thrashes per-XCD L2. Round-13: revert to SPLIT chunk
// passes (launch boundary = window barrier), keep the wins that were
// masked: merged-polarity CSR (pol bit in srcs[31], cnts precomputed),
// unroll-2 gather loops (2 gathers in flight/lane), fused chunk-3+update.
// Build (two-level partition + LDS-staged merged localsort) unchanged.

#define GAB 256    // blocks for build hist/scatter passes
#define BB  1024   // threads for build hist/scatter passes
#define CAPE 26624 // LDS staging capacity (entries) per super-bucket (104KB)

static inline int cdiv_h(long long a, long long b) { return (int)((a + b - 1) / b); }

__device__ inline float bf_lo(unsigned u) { return __uint_as_float(u << 16); }
__device__ inline float bf_hi(unsigned u) { return __uint_as_float(u & 0xffff0000u); }
__device__ inline unsigned packy(float a, float b) {
    unsigned ua = __float_as_uint(a), ub = __float_as_uint(b);
    ua = (ua + 0x7fffu + ((ua >> 16) & 1u)) >> 16;
    ub = (ub + 0x7fffu + ((ub >> 16) & 1u)) & 0xffff0000u;
    return ua | ub;
}

// ---------------- build ----------------

// one pass over an edge list: histogram BOTH views (v by trg>>sv, c by src>>sc)
__global__ __launch_bounds__(BB) void hist_both(
    const int* __restrict__ keyV, const int* __restrict__ keyC,
    int e, int chunk, int sv, int sc, int nbv, int nbc,
    unsigned* __restrict__ histV, unsigned* __restrict__ histC) {
    extern __shared__ unsigned h[];  // nbv*4 + nbc*4 (4-way replicated)
    unsigned* hv = h;
    unsigned* hc = h + nbv * 4;
    int blk = blockIdx.x, tid = threadIdx.x;
    for (int i = tid; i < (nbv + nbc) * 4; i += blockDim.x) h[i] = 0u;
    __syncthreads();
    int s = blk * chunk, epos = min(e, s + chunk);
    int r = tid & 3;
    for (int i = s + tid; i < epos; i += blockDim.x) {
        atomicAdd(&hv[(((unsigned)(keyV[i] >> sv)) << 2) | r], 1u);
        atomicAdd(&hc[(((unsigned)(keyC[i] >> sc)) << 2) | r], 1u);
    }
    __syncthreads();
    for (int i = tid; i < nbv; i += blockDim.x)
        histV[(size_t)i * GAB + blk] = hv[4 * i] + hv[4 * i + 1] + hv[4 * i + 2] + hv[4 * i + 3];
    for (int i = tid; i < nbc; i += blockDim.x)
        histC[(size_t)i * GAB + blk] = hc[4 * i] + hc[4 * i + 1] + hc[4 * i + 2] + hc[4 * i + 3];
}

__global__ void rowscan256(const unsigned* __restrict__ hist, unsigned* __restrict__ rowscan,
                           unsigned* __restrict__ row_total) {
    __shared__ unsigned ts[256];
    int b = blockIdx.x, t = threadIdx.x;
    unsigned v0 = hist[(size_t)b * GAB + t];
    ts[t] = v0;
    __syncthreads();
    for (int off = 1; off < 256; off <<= 1) {
        unsigned v = (t >= off) ? ts[t - off] : 0u;
        __syncthreads();
        ts[t] += v;
        __syncthreads();
    }
    rowscan[(size_t)b * GAB + t] = ts[t] - v0;
    if (t == 255) row_total[b] = ts[255];
}

// exclusive scan of (totP+totN) -> base[0..nb]; baseNeg[i] = base[i] + totP[i]
__global__ void basescan2(const unsigned* __restrict__ totP, const unsigned* __restrict__ totN,
                          unsigned* __restrict__ base, unsigned* __restrict__ baseNeg, int nb) {
    __shared__ unsigned a[2048];
    __shared__ unsigned ts[1024];
    int t = threadIdx.x;
    a[t] = (t < nb) ? (totP[t] + totN[t]) : 0u;
    a[t + 1024] = (t + 1024 < nb) ? (totP[t + 1024] + totN[t + 1024]) : 0u;
    __syncthreads();
    unsigned a0 = a[2 * t], a1 = a[2 * t + 1];
    unsigned sum = a0 + a1;
    ts[t] = sum;
    __syncthreads();
    for (int off = 1; off < 1024; off <<= 1) {
        unsigned v = (t >= off) ? ts[t - off] : 0u;
        __syncthreads();
        ts[t] += v;
        __syncthreads();
    }
    unsigned b0 = ts[t] - sum;
    if (2 * t <= nb) base[2 * t] = b0;
    if (2 * t + 1 <= nb) base[2 * t + 1] = b0 + a0;
    if (2 * t < nb) baseNeg[2 * t] = b0 + totP[2 * t];
    if (2 * t + 1 < nb) baseNeg[2 * t + 1] = b0 + a0 + totP[2 * t + 1];
}

// coarse scatter: bucket by key>>kshift; entry = (pay << kshift) | (key & mask)
__global__ __launch_bounds__(BB) void scatter_sb(
    const int* __restrict__ key, const int* __restrict__ pay,
    int e, int chunk, int kshift, int nb,
    const unsigned* __restrict__ rowscan, const unsigned* __restrict__ base,
    unsigned* __restrict__ out) {
    extern __shared__ unsigned cur[];
    int blk = blockIdx.x, tid = threadIdx.x;
    for (int i = tid; i < nb; i += blockDim.x)
        cur[i] = base[i] + rowscan[(size_t)i * GAB + blk];
    __syncthreads();
    int s = blk * chunk, epos = min(e, s + chunk);
    unsigned mask = (1u << kshift) - 1u;
    for (int i = s + tid; i < epos; i += blockDim.x) {
        int k = key[i];
        int b = k >> kshift;
        unsigned p = atomicAdd(&cur[b], 1u);
        out[p] = ((unsigned)pay[i] << kshift) | ((unsigned)k & mask);
    }
}

// merged v-view localsort, LDS-staged: SB = 1024 vars, [pos|neg] segments.
// entry = (c<<10)|(v&1023); key = (v&1023)<<2 | chunk(c). srcs = (pol<<31)|c.
__global__ __launch_bounds__(1024) void localsort_v_m(
    const unsigned* __restrict__ ent, const unsigned* __restrict__ base,
    const unsigned* __restrict__ baseNeg, int nsb, int nv, int cs,
    unsigned* __restrict__ srcs, unsigned* __restrict__ rp, unsigned* __restrict__ cnts) {
    __shared__ unsigned h[4096];
    __shared__ unsigned ts[1024];
    __shared__ unsigned buf[CAPE];
    int s = blockIdx.x, t = threadIdx.x;
    unsigned sb = base[s], pe = baseNeg[s], se = base[s + 1];
    bool fits = (se - sb) <= (unsigned)CAPE;
    for (int k = 0; k < 4; ++k) h[t * 4 + k] = 0u;
    __syncthreads();
    for (unsigned i = sb + t; i < pe; i += 1024) {  // count pos
        unsigned u = ent[i];
        atomicAdd(&h[((u & 1023u) << 2) | ((u >> 10) >> cs)], 1u);
    }
    __syncthreads();
    unsigned pc[4];
    for (int k = 0; k < 4; ++k) pc[k] = h[t * 4 + k];
    __syncthreads();
    for (unsigned i = pe + t; i < se; i += 1024) {  // count neg on top
        unsigned u = ent[i];
        atomicAdd(&h[((u & 1023u) << 2) | ((u >> 10) >> cs)], 1u);
    }
    __syncthreads();
    unsigned v0[4];
    unsigned sum = 0;
    for (int k = 0; k < 4; ++k) { v0[k] = h[t * 4 + k]; sum += v0[k]; }
    ts[t] = sum;
    __syncthreads();
    for (int off = 1; off < 1024; off <<= 1) {
        unsigned x = (t >= off) ? ts[t - off] : 0u;
        __syncthreads();
        ts[t] += x;
        __syncthreads();
    }
    unsigned ex = ts[t] - sum;
    unsigned hx[4];
    for (int k = 0; k < 4; ++k) { hx[k] = ex; ex += v0[k]; }
    int node = s * 1024 + t;
    if (node < nv) {
        for (int ch = 0; ch < 4; ++ch) rp[(size_t)node * 4 + ch] = sb + hx[ch];
        unsigned cp = pc[0] + pc[1] + pc[2] + pc[3];
        unsigned tot = v0[0] + v0[1] + v0[2] + v0[3];
        cnts[node] = (cp << 16) | (tot - cp);
    }
    if (s == nsb - 1 && t == 0) rp[(size_t)nv * 4] = se;
    for (int k = 0; k < 4; ++k) h[t * 4 + k] = hx[k];
    __syncthreads();
    if (fits) {
        for (unsigned i = sb + t; i < pe; i += 1024) {
            unsigned u = ent[i];
            unsigned p = atomicAdd(&h[((u & 1023u) << 2) | ((u >> 10) >> cs)], 1u);
            buf[p] = u >> 10;
        }
        for (unsigned i = pe + t; i < se; i += 1024) {
            unsigned u = ent[i];
            unsigned p = atomicAdd(&h[((u & 1023u) << 2) | ((u >> 10) >> cs)], 1u);
            buf[p] = 0x80000000u | (u >> 10);
        }
        __syncthreads();
        unsigned n = se - sb;
        for (unsigned i = t; i < n; i += 1024) srcs[sb + i] = buf[i];
    } else {  // overflow fallback: direct global scatter (correct, slower)
        for (unsigned i = sb + t; i < pe; i += 1024) {
            unsigned u = ent[i];
            unsigned p = atomicAdd(&h[((u & 1023u) << 2) | ((u >> 10) >> cs)], 1u);
            srcs[sb + p] = u >> 10;
        }
        for (unsigned i = pe + t; i < se; i += 1024) {
            unsigned u = ent[i];
            unsigned p = atomicAdd(&h[((u & 1023u) << 2) | ((u >> 10) >> cs)], 1u);
            srcs[sb + p] = 0x80000000u | (u >> 10);
        }
    }
}

// merged c-view localsort, LDS-staged: SB = 4096 clauses. entry = (v<<12)|(c&4095)
__global__ __launch_bounds__(1024) void localsort_c_m(
    const unsigned* __restrict__ ent, const unsigned* __restrict__ base,
    const unsigned* __restrict__ baseNeg, int nsb, int nc,
    unsigned* __restrict__ srcs, unsigned* __restrict__ rp, unsigned* __restrict__ cnts) {
    __shared__ unsigned h[4096];
    __shared__ unsigned ts[1024];
    __shared__ unsigned buf[CAPE];
    int s = blockIdx.x, t = threadIdx.x;
    unsigned sb = base[s], pe = baseNeg[s], se = base[s + 1];
    bool fits = (se - sb) <= (unsigned)CAPE;
    for (int k = 0; k < 4; ++k) h[t * 4 + k] = 0u;
    __syncthreads();
    for (unsigned i = sb + t; i < pe; i += 1024)
        atomicAdd(&h[ent[i] & 4095u], 1u);
    __syncthreads();
    unsigned pc[4];
    for (int k = 0; k < 4; ++k) pc[k] = h[t * 4 + k];
    __syncthreads();
    for (unsigned i = pe + t; i < se; i += 1024)
        atomicAdd(&h[ent[i] & 4095u], 1u);
    __syncthreads();
    unsigned v0[4];
    unsigned sum = 0;
    for (int k = 0; k < 4; ++k) { v0[k] = h[t * 4 + k]; sum += v0[k]; }
    ts[t] = sum;
    __syncthreads();
    for (int off = 1; off < 1024; off <<= 1) {
        unsigned x = (t >= off) ? ts[t - off] : 0u;
        __syncthreads();
        ts[t] += x;
        __syncthreads();
    }
    unsigned ex = ts[t] - sum;
    unsigned hx[4];
    for (int k = 0; k < 4; ++k) { hx[k] = ex; ex += v0[k]; }
    int node0 = s * 4096 + t * 4;
    for (int k = 0; k < 4; ++k) {
        int node = node0 + k;
        if (node < nc) {
            rp[node] = sb + hx[k];
            cnts[node] = (pc[k] << 16) | (v0[k] - pc[k]);
        }
    }
    if (s == nsb - 1 && t == 0) rp[nc] = se;
    for (int k = 0; k < 4; ++k) h[t * 4 + k] = hx[k];
    __syncthreads();
    if (fits) {
        for (unsigned i = sb + t; i < pe; i += 1024) {
            unsigned u = ent[i];
            unsigned p = atomicAdd(&h[u & 4095u], 1u);
            buf[p] = u >> 12;
        }
        for (unsigned i = pe + t; i < se; i += 1024) {
            unsigned u = ent[i];
            unsigned p = atomicAdd(&h[u & 4095u], 1u);
            buf[p] = 0x80000000u | (u >> 12);
        }
        __syncthreads();
        unsigned n = se - sb;
        for (unsigned i = t; i < n; i += 1024) srcs[sb + i] = buf[i];
    } else {
        for (unsigned i = sb + t; i < pe; i += 1024) {
            unsigned u = ent[i];
            unsigned p = atomicAdd(&h[u & 4095u], 1u);
            srcs[sb + p] = u >> 12;
        }
        for (unsigned i = pe + t; i < se; i += 1024) {
            unsigned u = ent[i];
            unsigned p = atomicAdd(&h[u & 4095u], 1u);
            srcs[sb + p] = 0x80000000u | (u >> 12);
        }
    }
}

// ---------------- node init ----------------

__global__ void init_c_kernel(const float* __restrict__ x, const float* __restrict__ deg,
                              const float* __restrict__ W0, const float* __restrict__ b0,
                              float2* __restrict__ xc, unsigned* __restrict__ yc, int n) {
    int i = blockIdx.x * blockDim.x + threadIdx.x;
    if (i >= n) return;
    float xi = x[i];
    float2 o = make_float2(fmaf(xi, W0[0], b0[0]), fmaf(xi, W0[1], b0[1]));
    xc[i] = o;
    float d = deg[i];
    float inv = (d > 0.f) ? rsqrtf(d) : 0.f;
    yc[i] = packy(inv * o.x, inv * o.y);
}

__global__ void init_v_kernel(const float* __restrict__ x, const float* __restrict__ deg,
                              const float* __restrict__ W0, const float* __restrict__ b0,
                              float2* __restrict__ xv, unsigned* __restrict__ yv, int n) {
    int i = blockIdx.x * blockDim.x + threadIdx.x;
    if (i >= n) return;
    float xi = x[i];
    float2 o = make_float2(fmaf(xi, W0[0], b0[0]), fmaf(xi, W0[1], b0[1]));
    xv[i] = o;
    float d = deg[i];
    float inv = (d > 0.f) ? rsqrtf(d) : 0.f;
    yv[i] = packy(inv * o.x, inv * o.y);
}

// ---------------- per-layer kernels (merged CSR, quad-split, unroll-2) ----------------

// gather-accumulate one merged segment [s0,e0) with unroll-2; lane offset q
__device__ inline void row_accum(const unsigned* __restrict__ srcs,
                                 const unsigned* __restrict__ y,
                                 unsigned s0, unsigned e0, int q,
                                 float& ax, float& ay, float& bx, float& by) {
    unsigned j = s0 + q;
    for (; j + 4 < e0; j += 8) {
        unsigned u0 = srcs[j], u1 = srcs[j + 4];
        unsigned y0 = y[u0 & 0x7fffffffu], y1 = y[u1 & 0x7fffffffu];
        float t0 = (u0 & 0x80000000u) ? 0.f : 1.f;
        float t1 = (u1 & 0x80000000u) ? 0.f : 1.f;
        float l0 = bf_lo(y0), h0 = bf_hi(y0);
        float l1 = bf_lo(y1), h1 = bf_hi(y1);
        ax = fmaf(t0, l0, ax); ay = fmaf(t0, h0, ay);
        bx = fmaf(1.f - t0, l0, bx); by = fmaf(1.f - t0, h0, by);
        ax = fmaf(t1, l1, ax); ay = fmaf(t1, h1, ay);
        bx = fmaf(1.f - t1, l1, bx); by = fmaf(1.f - t1, h1, by);
    }
    if (j < e0) {
        unsigned u = srcs[j];
        unsigned yw = y[u & 0x7fffffffu];
        float tp = (u & 0x80000000u) ? 0.f : 1.f;
        float lo = bf_lo(yw), hi = bf_hi(yw);
        ax = fmaf(tp, lo, ax); ay = fmaf(tp, hi, ay);
        bx = fmaf(1.f - tp, lo, bx); by = fmaf(1.f - tp, hi, by);
    }
}

// chunks k = 0..2: accumulate into acc (pos.xy, neg.zw). One launch per chunk
// keeps all blocks in the same 2MB yc window (L2-resident).
__global__ __launch_bounds__(256) void v_chunk_q(
    const unsigned* __restrict__ rp, const unsigned* __restrict__ srcs,
    const unsigned* __restrict__ yc, float4* __restrict__ acc, int nv, int k) {
    int gt = blockIdx.x * blockDim.x + threadIdx.x;
    int i = gt >> 2, q = gt & 3;
    if (i >= nv) return;
    unsigned s0 = rp[(size_t)i * 4 + k], e0 = rp[(size_t)i * 4 + k + 1];
    float ax = 0.f, ay = 0.f, bx = 0.f, by = 0.f;
    row_accum(srcs, yc, s0, e0, q, ax, ay, bx, by);
    for (int m = 1; m < 4; m <<= 1) {
        ax += __shfl_xor(ax, m, 4);
        ay += __shfl_xor(ay, m, 4);
        bx += __shfl_xor(bx, m, 4);
        by += __shfl_xor(by, m, 4);
    }
    if (q == 0) {
        float4 a = (k == 0) ? make_float4(0.f, 0.f, 0.f, 0.f) : acc[i];
        a.x += ax; a.y += ay; a.z += bx; a.w += by;
        acc[i] = a;
    }
}

// chunk k = 3 fused with the node update
__global__ __launch_bounds__(256) void v_chunk_last(
    const unsigned* __restrict__ rp, const unsigned* __restrict__ srcs,
    const unsigned* __restrict__ yc, const float4* __restrict__ acc,
    const unsigned* __restrict__ cnts, float2* __restrict__ xv,
    const float* __restrict__ deg_v, const float* __restrict__ W,
    const float* __restrict__ bias, unsigned* __restrict__ yv_out, int nv, int writeY) {
    int gt = blockIdx.x * blockDim.x + threadIdx.x;
    int i = gt >> 2, q = gt & 3;
    if (i >= nv) return;
    unsigned s0 = rp[(size_t)i * 4 + 3], e0 = rp[(size_t)i * 4 + 4];
    float ax = 0.f, ay = 0.f, bx = 0.f, by = 0.f;
    row_accum(srcs, yc, s0, e0, q, ax, ay, bx, by);
    for (int m = 1; m < 4; m <<= 1) {
        ax += __shfl_xor(ax, m, 4);
        ay += __shfl_xor(ay, m, 4);
        bx += __shfl_xor(bx, m, 4);
        by += __shfl_xor(by, m, 4);
    }
    if (q == 0) {
        float4 a = acc[i];
        ax += a.x; ay += a.y; bx += a.z; by += a.w;
        unsigned ct = cnts[i];
        float cp = (float)(ct >> 16), cn = (float)(ct & 0xffffu);
        float2 xi = xv[i];
        float dv = deg_v[i];
        float iv = (dv > 0.f) ? rsqrtf(dv) : 0.f;
        float m0 = fmaf(iv, ax, cp * xi.x);
        float m1 = fmaf(iv, ay, cp * xi.y);
        float m2 = fmaf(iv, bx, cn * xi.x);
        float m3 = fmaf(iv, by, cn * xi.y);
        float o0 = bias[0] + m0 * W[0] + m1 * W[2] + m2 * W[4] + m3 * W[6] + xi.x * W[8] + xi.y * W[10];
        float o1 = bias[1] + m0 * W[1] + m1 * W[3] + m2 * W[5] + m3 * W[7] + xi.x * W[9] + xi.y * W[11];
        xv[i] = make_float2(o0, o1);
        if (writeY) yv_out[i] = packy(iv * o0, iv * o1);
    }
}

// clause layer: merged row, unroll-2 gathers, fused update; optional xc store
__global__ __launch_bounds__(256) void c_layer_m(
    const unsigned* __restrict__ rp, const unsigned* __restrict__ srcs,
    const unsigned* __restrict__ cnts, const unsigned* __restrict__ yv,
    float2* __restrict__ xc, const float* __restrict__ deg_c,
    unsigned* __restrict__ yc, const float* __restrict__ W,
    const float* __restrict__ bias, int nc, int writeX) {
    int gt = blockIdx.x * blockDim.x + threadIdx.x;
    int i = gt >> 2, q = gt & 3;
    if (i >= nc) return;
    unsigned s0 = rp[i], e0 = rp[i + 1];
    float ax = 0.f, ay = 0.f, bx = 0.f, by = 0.f;
    row_accum(srcs, yv, s0, e0, q, ax, ay, bx, by);
    for (int m = 1; m < 4; m <<= 1) {
        ax += __shfl_xor(ax, m, 4);
        ay += __shfl_xor(ay, m, 4);
        bx += __shfl_xor(bx, m, 4);
        by += __shfl_xor(by, m, 4);
    }
    if (q == 0) {
        unsigned ct = cnts[i];
        float cp = (float)(ct >> 16), cn = (float)(ct & 0xffffu);
        float2 xi = xc[i];
        float dc = deg_c[i];
        float ic = (dc > 0.f) ? rsqrtf(dc) : 0.f;
        float m0 = fmaf(ic, ax, cp * xi.x);
        float m1 = fmaf(ic, ay, cp * xi.y);
        float m2 = fmaf(ic, bx, cn * xi.x);
        float m3 = fmaf(ic, by, cn * xi.y);
        float o0 = bias[0] + m0 * W[0] + m1 * W[2] + m2 * W[4] + m3 * W[6] + xi.x * W[8] + xi.y * W[10];
        float o1 = bias[1] + m0 * W[1] + m1 * W[3] + m2 * W[5] + m3 * W[7] + xi.x * W[9] + xi.y * W[11];
        if (writeX) xc[i] = make_float2(o0, o1);
        yc[i] = packy(ic * o0, ic * o1);
    }
}

// ---------------- fallback: global-atomic path ----------------

__global__ void init_nodes(const float* __restrict__ x, const float* __restrict__ deg,
                           const float* __restrict__ W0, const float* __restrict__ b0,
                           float2* __restrict__ xf, float* __restrict__ inv, int n) {
    int i = blockIdx.x * blockDim.x + threadIdx.x;
    if (i >= n) return;
    float xi = x[i];
    xf[i] = make_float2(fmaf(xi, W0[0], b0[0]), fmaf(xi, W0[1], b0[1]));
    float d = deg[i];
    inv[i] = (d > 0.0f) ? (1.0f / sqrtf(d)) : 0.0f;
}

__global__ void count_edges(const int* __restrict__ src, const int* __restrict__ trg,
                            float* __restrict__ cnt_src, float* __restrict__ cnt_trg, int e) {
    int i = blockIdx.x * blockDim.x + threadIdx.x;
    if (i >= e) return;
    atomicAdd(&cnt_src[src[i]], 1.0f);
    atomicAdd(&cnt_trg[trg[i]], 1.0f);
}

__global__ void edge_pass(const int* __restrict__ src, const int* __restrict__ trg,
                          const float2* __restrict__ xc, const float2* __restrict__ xv,
                          const float* __restrict__ inv_c, const float* __restrict__ inv_v,
                          float2* __restrict__ Sv, float2* __restrict__ Sc, int e) {
    int i = blockIdx.x * blockDim.x + threadIdx.x;
    if (i >= e) return;
    int c = src[i];
    int v = trg[i];
    float ic = inv_c[c], iv = inv_v[v];
    float2 a = xc[c];
    float2 b = xv[v];
    atomicAdd(&Sv[v].x, a.x * ic);
    atomicAdd(&Sv[v].y, a.y * ic);
    atomicAdd(&Sc[c].x, b.x * iv);
    atomicAdd(&Sc[c].y, b.y * iv);
}

__global__ void node_update(float2* __restrict__ x, const float2* __restrict__ Sp,
                            const float2* __restrict__ Sn, const float* __restrict__ inv,
                            const float* __restrict__ cp, const float* __restrict__ cn,
                            const float* __restrict__ W, const float* __restrict__ b, int n) {
    int i = blockIdx.x * blockDim.x + threadIdx.x;
    if (i >= n) return;
    float2 xi = x[i];
    float ii = inv[i];
    float2 sp = Sp[i], sn = Sn[i];
    float cpi = cp[i], cni = cn[i];
    float m0 = fmaf(ii, sp.x, cpi * xi.x);
    float m1 = fmaf(ii, sp.y, cpi * xi.y);
    float m2 = fmaf(ii, sn.x, cni * xi.x);
    float m3 = fmaf(ii, sn.y, cni * xi.y);
    float o0 = b[0] + m0 * W[0] + m1 * W[2] + m2 * W[4] + m3 * W[6] + xi.x * W[8] + xi.y * W[10];
    float o1 = b[1] + m0 * W[1] + m1 * W[3] + m2 * W[5] + m3 * W[7] + xi.x * W[9] + xi.y * W[11];
    x[i] = make_float2(o0, o1);
}

// ---------------- launch ----------------

extern "C" void kernel_launch(void* const* d_in, const int* in_sizes, int n_in,
                              void* d_out, int out_size, void* d_ws, size_t ws_size,
                              hipStream_t stream) {
    const float* x_clause   = (const float*)d_in[0];
    const float* x_variable = (const float*)d_in[1];
    const float* deg_clause = (const float*)d_in[2];
    const float* deg_var    = (const float*)d_in[3];
    const int*   pos_src    = (const int*)d_in[4];
    const int*   pos_trg    = (const int*)d_in[5];
    const int*   neg_src    = (const int*)d_in[6];
    const int*   neg_trg    = (const int*)d_in[7];
    const float* W0c        = (const float*)d_in[8];
    const float* b0c        = (const float*)d_in[9];
    const float* W0v        = (const float*)d_in[10];
    const float* b0v        = (const float*)d_in[11];
    const float* Wc         = (const float*)d_in[12];
    const float* bc         = (const float*)d_in[13];
    const float* Wv         = (const float*)d_in[14];
    const float* bv         = (const float*)d_in[15];

    const int nc = in_sizes[0];
    const int nv = in_sizes[1];
    const int e  = in_sizes[4];
    const int B = 256;

    const int NSBV = cdiv_h(nv, 1024);   // v super-buckets (1024 vars each)
    const int NSBC = cdiv_h(nc, 4096);   // c super-buckets (4096 clauses each)
    const int maxnb = NSBV > NSBC ? NSBV : NSBC;
    const bool pack_ok = (nc <= (1 << 21)) && (nv <= (1 << 19)) &&
                         (NSBV <= 2040) && (NSBC <= 2040);

    int cs = 0;  // clause-chunk shift: 4 chunks cover nc
    while ((4LL << cs) < nc) cs++;

    // -------- tier-1 layout: persistent merged CSRs + build/layer overlay --------
    {
        size_t off = 0;
        auto alloc = [&](size_t bytes) {
            void* p = (char*)d_ws + off;
            off += (bytes + 255) & ~(size_t)255;
            return p;
        };
        unsigned* srcs_v = (unsigned*)alloc((size_t)2 * e * 4);          // (pol<<31)|c
        unsigned* srcs_c = (unsigned*)alloc((size_t)2 * e * 4);          // (pol<<31)|v
        unsigned* rp_v   = (unsigned*)alloc((size_t)4 * (nv + 1) * 4);   // node-major [node*4+chunk]
        unsigned* rp_c   = (unsigned*)alloc((size_t)(nc + 1) * 4);
        unsigned* cnts_v = (unsigned*)alloc((size_t)nv * 4);             // (cp<<16)|cn
        unsigned* cnts_c = (unsigned*)alloc((size_t)nc * 4);
        const size_t overlay = off;
        // build-time view
        unsigned* temp    = (unsigned*)alloc((size_t)2 * e * 4);
        unsigned* histVP  = (unsigned*)alloc((size_t)maxnb * GAB * 4);
        unsigned* histVN  = (unsigned*)alloc((size_t)maxnb * GAB * 4);
        unsigned* histCP  = (unsigned*)alloc((size_t)maxnb * GAB * 4);
        unsigned* histCN  = (unsigned*)alloc((size_t)maxnb * GAB * 4);
        unsigned* rsVP    = (unsigned*)alloc((size_t)maxnb * GAB * 4);
        unsigned* rsVN    = (unsigned*)alloc((size_t)maxnb * GAB * 4);
        unsigned* rsCP    = (unsigned*)alloc((size_t)maxnb * GAB * 4);
        unsigned* rsCN    = (unsigned*)alloc((size_t)maxnb * GAB * 4);
        unsigned* totVP   = (unsigned*)alloc((size_t)maxnb * 4);
        unsigned* totVN   = (unsigned*)alloc((size_t)maxnb * 4);
        unsigned* totCP   = (unsigned*)alloc((size_t)maxnb * 4);
        unsigned* totCN   = (unsigned*)alloc((size_t)maxnb * 4);
        unsigned* baseV   = (unsigned*)alloc((size_t)(NSBV + 1) * 4);
        unsigned* baseVN  = (unsigned*)alloc((size_t)(NSBV + 1) * 4);
        unsigned* baseC   = (unsigned*)alloc((size_t)(NSBC + 1) * 4);
        unsigned* baseCN  = (unsigned*)alloc((size_t)(NSBC + 1) * 4);
        const size_t build_end = off;
        // layer-time view (overlaps build scratch; inits run AFTER build)
        off = overlay;
        float4*   accv    = (float4*)alloc((size_t)nv * 16);
        float2*   xc      = (float2*)alloc((size_t)nc * 8);
        unsigned* yc      = (unsigned*)alloc((size_t)nc * 4);
        unsigned* yvA     = (unsigned*)alloc((size_t)nv * 4);
        unsigned* yvB     = (unsigned*)alloc((size_t)nv * 4);
        const size_t layer_end = off;
        const size_t required = build_end > layer_end ? build_end : layer_end;

        if (required <= ws_size && pack_ok) {
            const int chunk = cdiv_h(e, GAB);
            // histograms: one pass per edge list computes BOTH views
            hist_both<<<GAB, BB, (size_t)(NSBV + NSBC) * 16, stream>>>(
                pos_trg, pos_src, e, chunk, 10, 12, NSBV, NSBC, histVP, histCP);
            hist_both<<<GAB, BB, (size_t)(NSBV + NSBC) * 16, stream>>>(
                neg_trg, neg_src, e, chunk, 10, 12, NSBV, NSBC, histVN, histCN);
            rowscan256<<<NSBV, B, 0, stream>>>(histVP, rsVP, totVP);
            rowscan256<<<NSBV, B, 0, stream>>>(histVN, rsVN, totVN);
            rowscan256<<<NSBC, B, 0, stream>>>(histCP, rsCP, totCP);
            rowscan256<<<NSBC, B, 0, stream>>>(histCN, rsCN, totCN);
            basescan2<<<1, 1024, 0, stream>>>(totVP, totVN, baseV, baseVN, NSBV);
            basescan2<<<1, 1024, 0, stream>>>(totCP, totCN, baseC, baseCN, NSBC);
            // V view: pos then neg into [pos|neg] SB segments, then LDS-staged localsort
            scatter_sb<<<GAB, BB, (size_t)NSBV * 4, stream>>>(pos_trg, pos_src, e, chunk,
                                                              10, NSBV, rsVP, baseV, temp);
            scatter_sb<<<GAB, BB, (size_t)NSBV * 4, stream>>>(neg_trg, neg_src, e, chunk,
                                                              10, NSBV, rsVN, baseVN, temp);
            localsort_v_m<<<NSBV, 1024, 0, stream>>>(temp, baseV, baseVN, NSBV, nv, cs,
                                                     srcs_v, rp_v, cnts_v);
            // C view
            scatter_sb<<<GAB, BB, (size_t)NSBC * 4, stream>>>(pos_src, pos_trg, e, chunk,
                                                              12, NSBC, rsCP, baseC, temp);
            scatter_sb<<<GAB, BB, (size_t)NSBC * 4, stream>>>(neg_src, neg_trg, e, chunk,
                                                              12, NSBC, rsCN, baseCN, temp);
            localsort_c_m<<<NSBC, 1024, 0, stream>>>(temp, baseC, baseCN, NSBC, nc,
                                                     srcs_c, rp_c, cnts_c);

            float2* xv = (float2*)d_out;  // updated in place each layer
            init_c_kernel<<<cdiv_h(nc, B), B, 0, stream>>>(x_clause, deg_clause, W0c, b0c, xc, yc, nc);
            init_v_kernel<<<cdiv_h(nv, B), B, 0, stream>>>(x_variable, deg_var, W0v, b0v, xv, yvA, nv);

            unsigned* ycur = yvA;  // yv of layer l
            unsigned* ynxt = yvB;  // yv of layer l+1
            for (int l = 0; l < 4; ++l) {
                for (int k = 0; k < 3; ++k) {
                    v_chunk_q<<<cdiv_h((long long)nv * 4, B), B, 0, stream>>>(
                        rp_v, srcs_v, yc, accv, nv, k);
                }
                v_chunk_last<<<cdiv_h((long long)nv * 4, B), B, 0, stream>>>(
                    rp_v, srcs_v, yc, accv, cnts_v, xv, deg_var,
                    Wv + l * 12, bv + l * 2, ynxt, nv, (l < 2) ? 1 : 0);
                if (l < 3) {
                    c_layer_m<<<cdiv_h((long long)nc * 4, B), B, 0, stream>>>(
                        rp_c, srcs_c, cnts_c, ycur, xc, deg_clause, yc,
                        Wc + l * 12, bc + l * 2, nc, (l < 2) ? 1 : 0);
                }
                unsigned* ty = ycur; ycur = ynxt; ynxt = ty;
            }
            return;
        }
    }

    // -------- fallback: global-atomic path --------
    char* p = (char*)d_ws;
    float2* Sv_pos = (float2*)p; p += (size_t)nv * sizeof(float2);
    float2* Sv_neg = (float2*)p; p += (size_t)nv * sizeof(float2);
    float2* Sc_pos = (float2*)p; p += (size_t)nc * sizeof(float2);
    float2* Sc_neg = (float2*)p; p += (size_t)nc * sizeof(float2);
    const size_t s_bytes = (size_t)(2 * nv + 2 * nc) * sizeof(float2);
    float2* xc2 = (float2*)p; p += (size_t)nc * sizeof(float2);
    float* inv_c = (float*)p; p += (size_t)nc * sizeof(float);
    float* inv_v = (float*)p; p += (size_t)nv * sizeof(float);
    float* cntc_pos = (float*)p; p += (size_t)nc * sizeof(float);
    float* cntc_neg = (float*)p; p += (size_t)nc * sizeof(float);
    float* cntv_pos = (float*)p; p += (size_t)nv * sizeof(float);
    float* cntv_neg = (float*)p; p += (size_t)nv * sizeof(float);
    const size_t cnt_bytes = (size_t)(2 * nc + 2 * nv) * sizeof(float);
    float2* xv = (float2*)d_out;

    hipMemsetAsync(Sv_pos, 0, s_bytes, stream);
    hipMemsetAsync(cntc_pos, 0, cnt_bytes, stream);
    init_nodes<<<cdiv_h(nc, B), B, 0, stream>>>(x_clause, deg_clause, W0c, b0c, xc2, inv_c, nc);
    init_nodes<<<cdiv_h(nv, B), B, 0, stream>>>(x_variable, deg_var, W0v, b0v, xv, inv_v, nv);
    count_edges<<<cdiv_h(e, B), B, 0, stream>>>(pos_src, pos_trg, cntc_pos, cntv_pos, e);
    count_edges<<<cdiv_h(e, B), B, 0, stream>>>(neg_src, neg_trg, cntc_neg, cntv_neg, e);
    for (int l = 0; l < 4; ++l) {
        edge_pass<<<cdiv_h(e, B), B, 0, stream>>>(pos_src, pos_trg, xc2, xv, inv_c, inv_v,
                                                  Sv_pos, Sc_pos, e);
        edge_pass<<<cdiv_h(e, B), B, 0, stream>>>(neg_src, neg_trg, xc2, xv, inv_c, inv_v,
                                                  Sv_neg, Sc_neg, e);
        node_update<<<cdiv_h(nv, B), B, 0, stream>>>(xv, Sv_pos, Sv_neg, inv_v,
                                                     cntv_pos, cntv_neg, Wv + l * 12, bv + l * 2, nv);
        node_update<<<cdiv_h(nc, B), B, 0, stream>>>(xc2, Sc_pos, Sc_neg, inv_c,
                                                     cntc_pos, cntc_neg, Wc + l * 12, bc + l * 2, nc);
        if (l < 3) hipMemsetAsync(Sv_pos, 0, s_bytes, stream);
    }
}

// Round 14
// 922.741 us; speedup vs baseline: 1.2030x; 1.0318x over previous
//
#include <hip/hip_runtime.h>

// G4GCN: 4-layer linear bipartite GNN (clauses <-> variables), feature dim 2.
//
// Round-13 state (952us): c_layer 3x81us (latency-bound short-row gathers),
// v-side 4 chunk passes/layer (~85us incl. rp+acc restreaming), build ~300us.
// Round-14:
//  - CHUNKS=2 (launch-param only; build's 2-bit chunk field supports it):
//    yc window 4MB (= per-XCD L2). Halves v-side passes -> saves rp/acc
//    streams + launches. GUARD: v_chunk_q FETCH >= 300MB means the 4MB
//    window thrashed -> revert to 4 chunks.
//  - pair-split c_layer (2 lanes/clause): merged clause rows mean only 6
//    entries; quad-split wasted lanes on reduce/epilogue. Stride-2 unroll-2.
// Everything else from round 13 (merged-polarity CSR, LDS-staged localsort,
// two-level partition, fused last-chunk+update, yv ping-pong) unchanged.

#define GAB 256    // blocks for build hist/scatter passes
#define BB  1024   // threads for build hist/scatter passes
#define CAPE 26624 // LDS staging capacity (entries) per super-bucket (104KB)
#define CHUNKS 2   // yc chunk-windows for the v-side gather

static inline int cdiv_h(long long a, long long b) { return (int)((a + b - 1) / b); }

__device__ inline float bf_lo(unsigned u) { return __uint_as_float(u << 16); }
__device__ inline float bf_hi(unsigned u) { return __uint_as_float(u & 0xffff0000u); }
__device__ inline unsigned packy(float a, float b) {
    unsigned ua = __float_as_uint(a), ub = __float_as_uint(b);
    ua = (ua + 0x7fffu + ((ua >> 16) & 1u)) >> 16;
    ub = (ub + 0x7fffu + ((ub >> 16) & 1u)) & 0xffff0000u;
    return ua | ub;
}

// ---------------- build ----------------

// one pass over an edge list: histogram BOTH views (v by trg>>sv, c by src>>sc)
__global__ __launch_bounds__(BB) void hist_both(
    const int* __restrict__ keyV, const int* __restrict__ keyC,
    int e, int chunk, int sv, int sc, int nbv, int nbc,
    unsigned* __restrict__ histV, unsigned* __restrict__ histC) {
    extern __shared__ unsigned h[];  // nbv*4 + nbc*4 (4-way replicated)
    unsigned* hv = h;
    unsigned* hc = h + nbv * 4;
    int blk = blockIdx.x, tid = threadIdx.x;
    for (int i = tid; i < (nbv + nbc) * 4; i += blockDim.x) h[i] = 0u;
    __syncthreads();
    int s = blk * chunk, epos = min(e, s + chunk);
    int r = tid & 3;
    for (int i = s + tid; i < epos; i += blockDim.x) {
        atomicAdd(&hv[(((unsigned)(keyV[i] >> sv)) << 2) | r], 1u);
        atomicAdd(&hc[(((unsigned)(keyC[i] >> sc)) << 2) | r], 1u);
    }
    __syncthreads();
    for (int i = tid; i < nbv; i += blockDim.x)
        histV[(size_t)i * GAB + blk] = hv[4 * i] + hv[4 * i + 1] + hv[4 * i + 2] + hv[4 * i + 3];
    for (int i = tid; i < nbc; i += blockDim.x)
        histC[(size_t)i * GAB + blk] = hc[4 * i] + hc[4 * i + 1] + hc[4 * i + 2] + hc[4 * i + 3];
}

__global__ void rowscan256(const unsigned* __restrict__ hist, unsigned* __restrict__ rowscan,
                           unsigned* __restrict__ row_total) {
    __shared__ unsigned ts[256];
    int b = blockIdx.x, t = threadIdx.x;
    unsigned v0 = hist[(size_t)b * GAB + t];
    ts[t] = v0;
    __syncthreads();
    for (int off = 1; off < 256; off <<= 1) {
        unsigned v = (t >= off) ? ts[t - off] : 0u;
        __syncthreads();
        ts[t] += v;
        __syncthreads();
    }
    rowscan[(size_t)b * GAB + t] = ts[t] - v0;
    if (t == 255) row_total[b] = ts[255];
}

// exclusive scan of (totP+totN) -> base[0..nb]; baseNeg[i] = base[i] + totP[i]
__global__ void basescan2(const unsigned* __restrict__ totP, const unsigned* __restrict__ totN,
                          unsigned* __restrict__ base, unsigned* __restrict__ baseNeg, int nb) {
    __shared__ unsigned a[2048];
    __shared__ unsigned ts[1024];
    int t = threadIdx.x;
    a[t] = (t < nb) ? (totP[t] + totN[t]) : 0u;
    a[t + 1024] = (t + 1024 < nb) ? (totP[t + 1024] + totN[t + 1024]) : 0u;
    __syncthreads();
    unsigned a0 = a[2 * t], a1 = a[2 * t + 1];
    unsigned sum = a0 + a1;
    ts[t] = sum;
    __syncthreads();
    for (int off = 1; off < 1024; off <<= 1) {
        unsigned v = (t >= off) ? ts[t - off] : 0u;
        __syncthreads();
        ts[t] += v;
        __syncthreads();
    }
    unsigned b0 = ts[t] - sum;
    if (2 * t <= nb) base[2 * t] = b0;
    if (2 * t + 1 <= nb) base[2 * t + 1] = b0 + a0;
    if (2 * t < nb) baseNeg[2 * t] = b0 + totP[2 * t];
    if (2 * t + 1 < nb) baseNeg[2 * t + 1] = b0 + a0 + totP[2 * t + 1];
}

// coarse scatter: bucket by key>>kshift; entry = (pay << kshift) | (key & mask)
__global__ __launch_bounds__(BB) void scatter_sb(
    const int* __restrict__ key, const int* __restrict__ pay,
    int e, int chunk, int kshift, int nb,
    const unsigned* __restrict__ rowscan, const unsigned* __restrict__ base,
    unsigned* __restrict__ out) {
    extern __shared__ unsigned cur[];
    int blk = blockIdx.x, tid = threadIdx.x;
    for (int i = tid; i < nb; i += blockDim.x)
        cur[i] = base[i] + rowscan[(size_t)i * GAB + blk];
    __syncthreads();
    int s = blk * chunk, epos = min(e, s + chunk);
    unsigned mask = (1u << kshift) - 1u;
    for (int i = s + tid; i < epos; i += blockDim.x) {
        int k = key[i];
        int b = k >> kshift;
        unsigned p = atomicAdd(&cur[b], 1u);
        out[p] = ((unsigned)pay[i] << kshift) | ((unsigned)k & mask);
    }
}

// merged v-view localsort, LDS-staged: SB = 1024 vars, [pos|neg] segments.
// entry = (c<<10)|(v&1023); key = (v&1023)<<2 | chunk(c). srcs = (pol<<31)|c.
__global__ __launch_bounds__(1024) void localsort_v_m(
    const unsigned* __restrict__ ent, const unsigned* __restrict__ base,
    const unsigned* __restrict__ baseNeg, int nsb, int nv, int cs,
    unsigned* __restrict__ srcs, unsigned* __restrict__ rp, unsigned* __restrict__ cnts) {
    __shared__ unsigned h[4096];
    __shared__ unsigned ts[1024];
    __shared__ unsigned buf[CAPE];
    int s = blockIdx.x, t = threadIdx.x;
    unsigned sb = base[s], pe = baseNeg[s], se = base[s + 1];
    bool fits = (se - sb) <= (unsigned)CAPE;
    for (int k = 0; k < 4; ++k) h[t * 4 + k] = 0u;
    __syncthreads();
    for (unsigned i = sb + t; i < pe; i += 1024) {  // count pos
        unsigned u = ent[i];
        atomicAdd(&h[((u & 1023u) << 2) | ((u >> 10) >> cs)], 1u);
    }
    __syncthreads();
    unsigned pc[4];
    for (int k = 0; k < 4; ++k) pc[k] = h[t * 4 + k];
    __syncthreads();
    for (unsigned i = pe + t; i < se; i += 1024) {  // count neg on top
        unsigned u = ent[i];
        atomicAdd(&h[((u & 1023u) << 2) | ((u >> 10) >> cs)], 1u);
    }
    __syncthreads();
    unsigned v0[4];
    unsigned sum = 0;
    for (int k = 0; k < 4; ++k) { v0[k] = h[t * 4 + k]; sum += v0[k]; }
    ts[t] = sum;
    __syncthreads();
    for (int off = 1; off < 1024; off <<= 1) {
        unsigned x = (t >= off) ? ts[t - off] : 0u;
        __syncthreads();
        ts[t] += x;
        __syncthreads();
    }
    unsigned ex = ts[t] - sum;
    unsigned hx[4];
    for (int k = 0; k < 4; ++k) { hx[k] = ex; ex += v0[k]; }
    int node = s * 1024 + t;
    if (node < nv) {
        for (int ch = 0; ch < 4; ++ch) rp[(size_t)node * 4 + ch] = sb + hx[ch];
        unsigned cp = pc[0] + pc[1] + pc[2] + pc[3];
        unsigned tot = v0[0] + v0[1] + v0[2] + v0[3];
        cnts[node] = (cp << 16) | (tot - cp);
    }
    if (s == nsb - 1 && t == 0) rp[(size_t)nv * 4] = se;
    for (int k = 0; k < 4; ++k) h[t * 4 + k] = hx[k];
    __syncthreads();
    if (fits) {
        for (unsigned i = sb + t; i < pe; i += 1024) {
            unsigned u = ent[i];
            unsigned p = atomicAdd(&h[((u & 1023u) << 2) | ((u >> 10) >> cs)], 1u);
            buf[p] = u >> 10;
        }
        for (unsigned i = pe + t; i < se; i += 1024) {
            unsigned u = ent[i];
            unsigned p = atomicAdd(&h[((u & 1023u) << 2) | ((u >> 10) >> cs)], 1u);
            buf[p] = 0x80000000u | (u >> 10);
        }
        __syncthreads();
        unsigned n = se - sb;
        for (unsigned i = t; i < n; i += 1024) srcs[sb + i] = buf[i];
    } else {  // overflow fallback: direct global scatter (correct, slower)
        for (unsigned i = sb + t; i < pe; i += 1024) {
            unsigned u = ent[i];
            unsigned p = atomicAdd(&h[((u & 1023u) << 2) | ((u >> 10) >> cs)], 1u);
            srcs[sb + p] = u >> 10;
        }
        for (unsigned i = pe + t; i < se; i += 1024) {
            unsigned u = ent[i];
            unsigned p = atomicAdd(&h[((u & 1023u) << 2) | ((u >> 10) >> cs)], 1u);
            srcs[sb + p] = 0x80000000u | (u >> 10);
        }
    }
}

// merged c-view localsort, LDS-staged: SB = 4096 clauses. entry = (v<<12)|(c&4095)
__global__ __launch_bounds__(1024) void localsort_c_m(
    const unsigned* __restrict__ ent, const unsigned* __restrict__ base,
    const unsigned* __restrict__ baseNeg, int nsb, int nc,
    unsigned* __restrict__ srcs, unsigned* __restrict__ rp, unsigned* __restrict__ cnts) {
    __shared__ unsigned h[4096];
    __shared__ unsigned ts[1024];
    __shared__ unsigned buf[CAPE];
    int s = blockIdx.x, t = threadIdx.x;
    unsigned sb = base[s], pe = baseNeg[s], se = base[s + 1];
    bool fits = (se - sb) <= (unsigned)CAPE;
    for (int k = 0; k < 4; ++k) h[t * 4 + k] = 0u;
    __syncthreads();
    for (unsigned i = sb + t; i < pe; i += 1024)
        atomicAdd(&h[ent[i] & 4095u], 1u);
    __syncthreads();
    unsigned pc[4];
    for (int k = 0; k < 4; ++k) pc[k] = h[t * 4 + k];
    __syncthreads();
    for (unsigned i = pe + t; i < se; i += 1024)
        atomicAdd(&h[ent[i] & 4095u], 1u);
    __syncthreads();
    unsigned v0[4];
    unsigned sum = 0;
    for (int k = 0; k < 4; ++k) { v0[k] = h[t * 4 + k]; sum += v0[k]; }
    ts[t] = sum;
    __syncthreads();
    for (int off = 1; off < 1024; off <<= 1) {
        unsigned x = (t >= off) ? ts[t - off] : 0u;
        __syncthreads();
        ts[t] += x;
        __syncthreads();
    }
    unsigned ex = ts[t] - sum;
    unsigned hx[4];
    for (int k = 0; k < 4; ++k) { hx[k] = ex; ex += v0[k]; }
    int node0 = s * 4096 + t * 4;
    for (int k = 0; k < 4; ++k) {
        int node = node0 + k;
        if (node < nc) {
            rp[node] = sb + hx[k];
            cnts[node] = (pc[k] << 16) | (v0[k] - pc[k]);
        }
    }
    if (s == nsb - 1 && t == 0) rp[nc] = se;
    for (int k = 0; k < 4; ++k) h[t * 4 + k] = hx[k];
    __syncthreads();
    if (fits) {
        for (unsigned i = sb + t; i < pe; i += 1024) {
            unsigned u = ent[i];
            unsigned p = atomicAdd(&h[u & 4095u], 1u);
            buf[p] = u >> 12;
        }
        for (unsigned i = pe + t; i < se; i += 1024) {
            unsigned u = ent[i];
            unsigned p = atomicAdd(&h[u & 4095u], 1u);
            buf[p] = 0x80000000u | (u >> 12);
        }
        __syncthreads();
        unsigned n = se - sb;
        for (unsigned i = t; i < n; i += 1024) srcs[sb + i] = buf[i];
    } else {
        for (unsigned i = sb + t; i < pe; i += 1024) {
            unsigned u = ent[i];
            unsigned p = atomicAdd(&h[u & 4095u], 1u);
            srcs[sb + p] = u >> 12;
        }
        for (unsigned i = pe + t; i < se; i += 1024) {
            unsigned u = ent[i];
            unsigned p = atomicAdd(&h[u & 4095u], 1u);
            srcs[sb + p] = 0x80000000u | (u >> 12);
        }
    }
}

// ---------------- node init ----------------

__global__ void init_c_kernel(const float* __restrict__ x, const float* __restrict__ deg,
                              const float* __restrict__ W0, const float* __restrict__ b0,
                              float2* __restrict__ xc, unsigned* __restrict__ yc, int n) {
    int i = blockIdx.x * blockDim.x + threadIdx.x;
    if (i >= n) return;
    float xi = x[i];
    float2 o = make_float2(fmaf(xi, W0[0], b0[0]), fmaf(xi, W0[1], b0[1]));
    xc[i] = o;
    float d = deg[i];
    float inv = (d > 0.f) ? rsqrtf(d) : 0.f;
    yc[i] = packy(inv * o.x, inv * o.y);
}

__global__ void init_v_kernel(const float* __restrict__ x, const float* __restrict__ deg,
                              const float* __restrict__ W0, const float* __restrict__ b0,
                              float2* __restrict__ xv, unsigned* __restrict__ yv, int n) {
    int i = blockIdx.x * blockDim.x + threadIdx.x;
    if (i >= n) return;
    float xi = x[i];
    float2 o = make_float2(fmaf(xi, W0[0], b0[0]), fmaf(xi, W0[1], b0[1]));
    xv[i] = o;
    float d = deg[i];
    float inv = (d > 0.f) ? rsqrtf(d) : 0.f;
    yv[i] = packy(inv * o.x, inv * o.y);
}

// ---------------- per-layer kernels (merged CSR, unroll-2) ----------------

// gather-accumulate one merged segment [s0,e0), lane offset q, stride S
template <int S>
__device__ inline void row_accum(const unsigned* __restrict__ srcs,
                                 const unsigned* __restrict__ y,
                                 unsigned s0, unsigned e0, int q,
                                 float& ax, float& ay, float& bx, float& by) {
    unsigned j = s0 + q;
    for (; j + S < e0; j += 2 * S) {
        unsigned u0 = srcs[j], u1 = srcs[j + S];
        unsigned y0 = y[u0 & 0x7fffffffu], y1 = y[u1 & 0x7fffffffu];
        float t0 = (u0 & 0x80000000u) ? 0.f : 1.f;
        float t1 = (u1 & 0x80000000u) ? 0.f : 1.f;
        float l0 = bf_lo(y0), h0 = bf_hi(y0);
        float l1 = bf_lo(y1), h1 = bf_hi(y1);
        ax = fmaf(t0, l0, ax); ay = fmaf(t0, h0, ay);
        bx = fmaf(1.f - t0, l0, bx); by = fmaf(1.f - t0, h0, by);
        ax = fmaf(t1, l1, ax); ay = fmaf(t1, h1, ay);
        bx = fmaf(1.f - t1, l1, bx); by = fmaf(1.f - t1, h1, by);
    }
    if (j < e0) {
        unsigned u = srcs[j];
        unsigned yw = y[u & 0x7fffffffu];
        float tp = (u & 0x80000000u) ? 0.f : 1.f;
        float lo = bf_lo(yw), hi = bf_hi(yw);
        ax = fmaf(tp, lo, ax); ay = fmaf(tp, hi, ay);
        bx = fmaf(1.f - tp, lo, bx); by = fmaf(1.f - tp, hi, by);
    }
}

// chunk pass k < CHUNKS-1: accumulate into acc (pos.xy, neg.zw). One launch
// per chunk keeps all blocks in the same yc window.
__global__ __launch_bounds__(256) void v_chunk_q(
    const unsigned* __restrict__ rp, const unsigned* __restrict__ srcs,
    const unsigned* __restrict__ yc, float4* __restrict__ acc, int nv, int k) {
    int gt = blockIdx.x * blockDim.x + threadIdx.x;
    int i = gt >> 2, q = gt & 3;
    if (i >= nv) return;
    unsigned s0 = rp[(size_t)i * 4 + k], e0 = rp[(size_t)i * 4 + k + 1];
    float ax = 0.f, ay = 0.f, bx = 0.f, by = 0.f;
    row_accum<4>(srcs, yc, s0, e0, q, ax, ay, bx, by);
    for (int m = 1; m < 4; m <<= 1) {
        ax += __shfl_xor(ax, m, 4);
        ay += __shfl_xor(ay, m, 4);
        bx += __shfl_xor(bx, m, 4);
        by += __shfl_xor(by, m, 4);
    }
    if (q == 0) {
        float4 a = (k == 0) ? make_float4(0.f, 0.f, 0.f, 0.f) : acc[i];
        a.x += ax; a.y += ay; a.z += bx; a.w += by;
        acc[i] = a;
    }
}

// last chunk (k = CHUNKS-1) fused with the node update
__global__ __launch_bounds__(256) void v_chunk_last(
    const unsigned* __restrict__ rp, const unsigned* __restrict__ srcs,
    const unsigned* __restrict__ yc, const float4* __restrict__ acc,
    const unsigned* __restrict__ cnts, float2* __restrict__ xv,
    const float* __restrict__ deg_v, const float* __restrict__ W,
    const float* __restrict__ bias, unsigned* __restrict__ yv_out,
    int nv, int k, int writeY) {
    int gt = blockIdx.x * blockDim.x + threadIdx.x;
    int i = gt >> 2, q = gt & 3;
    if (i >= nv) return;
    unsigned s0 = rp[(size_t)i * 4 + k], e0 = rp[(size_t)i * 4 + k + 1];
    float ax = 0.f, ay = 0.f, bx = 0.f, by = 0.f;
    row_accum<4>(srcs, yc, s0, e0, q, ax, ay, bx, by);
    for (int m = 1; m < 4; m <<= 1) {
        ax += __shfl_xor(ax, m, 4);
        ay += __shfl_xor(ay, m, 4);
        bx += __shfl_xor(bx, m, 4);
        by += __shfl_xor(by, m, 4);
    }
    if (q == 0) {
        float4 a = acc[i];
        ax += a.x; ay += a.y; bx += a.z; by += a.w;
        unsigned ct = cnts[i];
        float cp = (float)(ct >> 16), cn = (float)(ct & 0xffffu);
        float2 xi = xv[i];
        float dv = deg_v[i];
        float iv = (dv > 0.f) ? rsqrtf(dv) : 0.f;
        float m0 = fmaf(iv, ax, cp * xi.x);
        float m1 = fmaf(iv, ay, cp * xi.y);
        float m2 = fmaf(iv, bx, cn * xi.x);
        float m3 = fmaf(iv, by, cn * xi.y);
        float o0 = bias[0] + m0 * W[0] + m1 * W[2] + m2 * W[4] + m3 * W[6] + xi.x * W[8] + xi.y * W[10];
        float o1 = bias[1] + m0 * W[1] + m1 * W[3] + m2 * W[5] + m3 * W[7] + xi.x * W[9] + xi.y * W[11];
        xv[i] = make_float2(o0, o1);
        if (writeY) yv_out[i] = packy(iv * o0, iv * o1);
    }
}

// clause layer: PAIR-split (2 lanes/clause, merged rows mean ~6 entries),
// unroll-2, fused update; optional xc store
__global__ __launch_bounds__(256) void c_layer_m(
    const unsigned* __restrict__ rp, const unsigned* __restrict__ srcs,
    const unsigned* __restrict__ cnts, const unsigned* __restrict__ yv,
    float2* __restrict__ xc, const float* __restrict__ deg_c,
    unsigned* __restrict__ yc, const float* __restrict__ W,
    const float* __restrict__ bias, int nc, int writeX) {
    int gt = blockIdx.x * blockDim.x + threadIdx.x;
    int i = gt >> 1, q = gt & 1;
    if (i >= nc) return;
    unsigned s0 = rp[i], e0 = rp[i + 1];
    float ax = 0.f, ay = 0.f, bx = 0.f, by = 0.f;
    row_accum<2>(srcs, yv, s0, e0, q, ax, ay, bx, by);
    ax += __shfl_xor(ax, 1, 2);
    ay += __shfl_xor(ay, 1, 2);
    bx += __shfl_xor(bx, 1, 2);
    by += __shfl_xor(by, 1, 2);
    if (q == 0) {
        unsigned ct = cnts[i];
        float cp = (float)(ct >> 16), cn = (float)(ct & 0xffffu);
        float2 xi = xc[i];
        float dc = deg_c[i];
        float ic = (dc > 0.f) ? rsqrtf(dc) : 0.f;
        float m0 = fmaf(ic, ax, cp * xi.x);
        float m1 = fmaf(ic, ay, cp * xi.y);
        float m2 = fmaf(ic, bx, cn * xi.x);
        float m3 = fmaf(ic, by, cn * xi.y);
        float o0 = bias[0] + m0 * W[0] + m1 * W[2] + m2 * W[4] + m3 * W[6] + xi.x * W[8] + xi.y * W[10];
        float o1 = bias[1] + m0 * W[1] + m1 * W[3] + m2 * W[5] + m3 * W[7] + xi.x * W[9] + xi.y * W[11];
        if (writeX) xc[i] = make_float2(o0, o1);
        yc[i] = packy(ic * o0, ic * o1);
    }
}

// ---------------- fallback: global-atomic path ----------------

__global__ void init_nodes(const float* __restrict__ x, const float* __restrict__ deg,
                           const float* __restrict__ W0, const float* __restrict__ b0,
                           float2* __restrict__ xf, float* __restrict__ inv, int n) {
    int i = blockIdx.x * blockDim.x + threadIdx.x;
    if (i >= n) return;
    float xi = x[i];
    xf[i] = make_float2(fmaf(xi, W0[0], b0[0]), fmaf(xi, W0[1], b0[1]));
    float d = deg[i];
    inv[i] = (d > 0.0f) ? (1.0f / sqrtf(d)) : 0.0f;
}

__global__ void count_edges(const int* __restrict__ src, const int* __restrict__ trg,
                            float* __restrict__ cnt_src, float* __restrict__ cnt_trg, int e) {
    int i = blockIdx.x * blockDim.x + threadIdx.x;
    if (i >= e) return;
    atomicAdd(&cnt_src[src[i]], 1.0f);
    atomicAdd(&cnt_trg[trg[i]], 1.0f);
}

__global__ void edge_pass(const int* __restrict__ src, const int* __restrict__ trg,
                          const float2* __restrict__ xc, const float2* __restrict__ xv,
                          const float* __restrict__ inv_c, const float* __restrict__ inv_v,
                          float2* __restrict__ Sv, float2* __restrict__ Sc, int e) {
    int i = blockIdx.x * blockDim.x + threadIdx.x;
    if (i >= e) return;
    int c = src[i];
    int v = trg[i];
    float ic = inv_c[c], iv = inv_v[v];
    float2 a = xc[c];
    float2 b = xv[v];
    atomicAdd(&Sv[v].x, a.x * ic);
    atomicAdd(&Sv[v].y, a.y * ic);
    atomicAdd(&Sc[c].x, b.x * iv);
    atomicAdd(&Sc[c].y, b.y * iv);
}

__global__ void node_update(float2* __restrict__ x, const float2* __restrict__ Sp,
                            const float2* __restrict__ Sn, const float* __restrict__ inv,
                            const float* __restrict__ cp, const float* __restrict__ cn,
                            const float* __restrict__ W, const float* __restrict__ b, int n) {
    int i = blockIdx.x * blockDim.x + threadIdx.x;
    if (i >= n) return;
    float2 xi = x[i];
    float ii = inv[i];
    float2 sp = Sp[i], sn = Sn[i];
    float cpi = cp[i], cni = cn[i];
    float m0 = fmaf(ii, sp.x, cpi * xi.x);
    float m1 = fmaf(ii, sp.y, cpi * xi.y);
    float m2 = fmaf(ii, sn.x, cni * xi.x);
    float m3 = fmaf(ii, sn.y, cni * xi.y);
    float o0 = b[0] + m0 * W[0] + m1 * W[2] + m2 * W[4] + m3 * W[6] + xi.x * W[8] + xi.y * W[10];
    float o1 = b[1] + m0 * W[1] + m1 * W[3] + m2 * W[5] + m3 * W[7] + xi.x * W[9] + xi.y * W[11];
    x[i] = make_float2(o0, o1);
}

// ---------------- launch ----------------

extern "C" void kernel_launch(void* const* d_in, const int* in_sizes, int n_in,
                              void* d_out, int out_size, void* d_ws, size_t ws_size,
                              hipStream_t stream) {
    const float* x_clause   = (const float*)d_in[0];
    const float* x_variable = (const float*)d_in[1];
    const float* deg_clause = (const float*)d_in[2];
    const float* deg_var    = (const float*)d_in[3];
    const int*   pos_src    = (const int*)d_in[4];
    const int*   pos_trg    = (const int*)d_in[5];
    const int*   neg_src    = (const int*)d_in[6];
    const int*   neg_trg    = (const int*)d_in[7];
    const float* W0c        = (const float*)d_in[8];
    const float* b0c        = (const float*)d_in[9];
    const float* W0v        = (const float*)d_in[10];
    const float* b0v        = (const float*)d_in[11];
    const float* Wc         = (const float*)d_in[12];
    const float* bc         = (const float*)d_in[13];
    const float* Wv         = (const float*)d_in[14];
    const float* bv         = (const float*)d_in[15];

    const int nc = in_sizes[0];
    const int nv = in_sizes[1];
    const int e  = in_sizes[4];
    const int B = 256;

    const int NSBV = cdiv_h(nv, 1024);   // v super-buckets (1024 vars each)
    const int NSBC = cdiv_h(nc, 4096);   // c super-buckets (4096 clauses each)
    const int maxnb = NSBV > NSBC ? NSBV : NSBC;
    const bool pack_ok = (nc <= (1 << 21)) && (nv <= (1 << 19)) &&
                         (NSBV <= 2040) && (NSBC <= 2040);

    int cs = 0;  // clause-chunk shift: CHUNKS windows cover nc
    while (((long long)CHUNKS << cs) < nc) cs++;

    // -------- tier-1 layout: persistent merged CSRs + build/layer overlay --------
    {
        size_t off = 0;
        auto alloc = [&](size_t bytes) {
            void* p = (char*)d_ws + off;
            off += (bytes + 255) & ~(size_t)255;
            return p;
        };
        unsigned* srcs_v = (unsigned*)alloc((size_t)2 * e * 4);          // (pol<<31)|c
        unsigned* srcs_c = (unsigned*)alloc((size_t)2 * e * 4);          // (pol<<31)|v
        unsigned* rp_v   = (unsigned*)alloc((size_t)4 * (nv + 1) * 4);   // node-major [node*4+chunk]
        unsigned* rp_c   = (unsigned*)alloc((size_t)(nc + 1) * 4);
        unsigned* cnts_v = (unsigned*)alloc((size_t)nv * 4);             // (cp<<16)|cn
        unsigned* cnts_c = (unsigned*)alloc((size_t)nc * 4);
        const size_t overlay = off;
        // build-time view
        unsigned* temp    = (unsigned*)alloc((size_t)2 * e * 4);
        unsigned* histVP  = (unsigned*)alloc((size_t)maxnb * GAB * 4);
        unsigned* histVN  = (unsigned*)alloc((size_t)maxnb * GAB * 4);
        unsigned* histCP  = (unsigned*)alloc((size_t)maxnb * GAB * 4);
        unsigned* histCN  = (unsigned*)alloc((size_t)maxnb * GAB * 4);
        unsigned* rsVP    = (unsigned*)alloc((size_t)maxnb * GAB * 4);
        unsigned* rsVN    = (unsigned*)alloc((size_t)maxnb * GAB * 4);
        unsigned* rsCP    = (unsigned*)alloc((size_t)maxnb * GAB * 4);
        unsigned* rsCN    = (unsigned*)alloc((size_t)maxnb * GAB * 4);
        unsigned* totVP   = (unsigned*)alloc((size_t)maxnb * 4);
        unsigned* totVN   = (unsigned*)alloc((size_t)maxnb * 4);
        unsigned* totCP   = (unsigned*)alloc((size_t)maxnb * 4);
        unsigned* totCN   = (unsigned*)alloc((size_t)maxnb * 4);
        unsigned* baseV   = (unsigned*)alloc((size_t)(NSBV + 1) * 4);
        unsigned* baseVN  = (unsigned*)alloc((size_t)(NSBV + 1) * 4);
        unsigned* baseC   = (unsigned*)alloc((size_t)(NSBC + 1) * 4);
        unsigned* baseCN  = (unsigned*)alloc((size_t)(NSBC + 1) * 4);
        const size_t build_end = off;
        // layer-time view (overlaps build scratch; inits run AFTER build)
        off = overlay;
        float4*   accv    = (float4*)alloc((size_t)nv * 16);
        float2*   xc      = (float2*)alloc((size_t)nc * 8);
        unsigned* yc      = (unsigned*)alloc((size_t)nc * 4);
        unsigned* yvA     = (unsigned*)alloc((size_t)nv * 4);
        unsigned* yvB     = (unsigned*)alloc((size_t)nv * 4);
        const size_t layer_end = off;
        const size_t required = build_end > layer_end ? build_end : layer_end;

        if (required <= ws_size && pack_ok) {
            const int chunk = cdiv_h(e, GAB);
            // histograms: one pass per edge list computes BOTH views
            hist_both<<<GAB, BB, (size_t)(NSBV + NSBC) * 16, stream>>>(
                pos_trg, pos_src, e, chunk, 10, 12, NSBV, NSBC, histVP, histCP);
            hist_both<<<GAB, BB, (size_t)(NSBV + NSBC) * 16, stream>>>(
                neg_trg, neg_src, e, chunk, 10, 12, NSBV, NSBC, histVN, histCN);
            rowscan256<<<NSBV, B, 0, stream>>>(histVP, rsVP, totVP);
            rowscan256<<<NSBV, B, 0, stream>>>(histVN, rsVN, totVN);
            rowscan256<<<NSBC, B, 0, stream>>>(histCP, rsCP, totCP);
            rowscan256<<<NSBC, B, 0, stream>>>(histCN, rsCN, totCN);
            basescan2<<<1, 1024, 0, stream>>>(totVP, totVN, baseV, baseVN, NSBV);
            basescan2<<<1, 1024, 0, stream>>>(totCP, totCN, baseC, baseCN, NSBC);
            // V view: pos then neg into [pos|neg] SB segments, then LDS-staged localsort
            scatter_sb<<<GAB, BB, (size_t)NSBV * 4, stream>>>(pos_trg, pos_src, e, chunk,
                                                              10, NSBV, rsVP, baseV, temp);
            scatter_sb<<<GAB, BB, (size_t)NSBV * 4, stream>>>(neg_trg, neg_src, e, chunk,
                                                              10, NSBV, rsVN, baseVN, temp);
            localsort_v_m<<<NSBV, 1024, 0, stream>>>(temp, baseV, baseVN, NSBV, nv, cs,
                                                     srcs_v, rp_v, cnts_v);
            // C view
            scatter_sb<<<GAB, BB, (size_t)NSBC * 4, stream>>>(pos_src, pos_trg, e, chunk,
                                                              12, NSBC, rsCP, baseC, temp);
            scatter_sb<<<GAB, BB, (size_t)NSBC * 4, stream>>>(neg_src, neg_trg, e, chunk,
                                                              12, NSBC, rsCN, baseCN, temp);
            localsort_c_m<<<NSBC, 1024, 0, stream>>>(temp, baseC, baseCN, NSBC, nc,
                                                     srcs_c, rp_c, cnts_c);

            float2* xv = (float2*)d_out;  // updated in place each layer
            init_c_kernel<<<cdiv_h(nc, B), B, 0, stream>>>(x_clause, deg_clause, W0c, b0c, xc, yc, nc);
            init_v_kernel<<<cdiv_h(nv, B), B, 0, stream>>>(x_variable, deg_var, W0v, b0v, xv, yvA, nv);

            unsigned* ycur = yvA;  // yv of layer l
            unsigned* ynxt = yvB;  // yv of layer l+1
            for (int l = 0; l < 4; ++l) {
                for (int k = 0; k < CHUNKS - 1; ++k) {
                    v_chunk_q<<<cdiv_h((long long)nv * 4, B), B, 0, stream>>>(
                        rp_v, srcs_v, yc, accv, nv, k);
                }
                v_chunk_last<<<cdiv_h((long long)nv * 4, B), B, 0, stream>>>(
                    rp_v, srcs_v, yc, accv, cnts_v, xv, deg_var,
                    Wv + l * 12, bv + l * 2, ynxt, nv, CHUNKS - 1, (l < 2) ? 1 : 0);
                if (l < 3) {
                    c_layer_m<<<cdiv_h((long long)nc * 2, B), B, 0, stream>>>(
                        rp_c, srcs_c, cnts_c, ycur, xc, deg_clause, yc,
                        Wc + l * 12, bc + l * 2, nc, (l < 2) ? 1 : 0);
                }
                unsigned* ty = ycur; ycur = ynxt; ynxt = ty;
            }
            return;
        }
    }

    // -------- fallback: global-atomic path --------
    char* p = (char*)d_ws;
    float2* Sv_pos = (float2*)p; p += (size_t)nv * sizeof(float2);
    float2* Sv_neg = (float2*)p; p += (size_t)nv * sizeof(float2);
    float2* Sc_pos = (float2*)p; p += (size_t)nc * sizeof(float2);
    float2* Sc_neg = (float2*)p; p += (size_t)nc * sizeof(float2);
    const size_t s_bytes = (size_t)(2 * nv + 2 * nc) * sizeof(float2);
    float2* xc2 = (float2*)p; p += (size_t)nc * sizeof(float2);
    float* inv_c = (float*)p; p += (size_t)nc * sizeof(float);
    float* inv_v = (float*)p; p += (size_t)nv * sizeof(float);
    float* cntc_pos = (float*)p; p += (size_t)nc * sizeof(float);
    float* cntc_neg = (float*)p; p += (size_t)nc * sizeof(float);
    float* cntv_pos = (float*)p; p += (size_t)nv * sizeof(float);
    float* cntv_neg = (float*)p; p += (size_t)nv * sizeof(float);
    const size_t cnt_bytes = (size_t)(2 * nc + 2 * nv) * sizeof(float);
    float2* xv = (float2*)d_out;

    hipMemsetAsync(Sv_pos, 0, s_bytes, stream);
    hipMemsetAsync(cntc_pos, 0, cnt_bytes, stream);
    init_nodes<<<cdiv_h(nc, B), B, 0, stream>>>(x_clause, deg_clause, W0c, b0c, xc2, inv_c, nc);
    init_nodes<<<cdiv_h(nv, B), B, 0, stream>>>(x_variable, deg_var, W0v, b0v, xv, inv_v, nv);
    count_edges<<<cdiv_h(e, B), B, 0, stream>>>(pos_src, pos_trg, cntc_pos, cntv_pos, e);
    count_edges<<<cdiv_h(e, B), B, 0, stream>>>(neg_src, neg_trg, cntc_neg, cntv_neg, e);
    for (int l = 0; l < 4; ++l) {
        edge_pass<<<cdiv_h(e, B), B, 0, stream>>>(pos_src, pos_trg, xc2, xv, inv_c, inv_v,
                                                  Sv_pos, Sc_pos, e);
        edge_pass<<<cdiv_h(e, B), B, 0, stream>>>(neg_src, neg_trg, xc2, xv, inv_c, inv_v,
                                                  Sv_neg, Sc_neg, e);
        node_update<<<cdiv_h(nv, B), B, 0, stream>>>(xv, Sv_pos, Sv_neg, inv_v,
                                                     cntv_pos, cntv_neg, Wv + l * 12, bv + l * 2, nv);
        node_update<<<cdiv_h(nc, B), B, 0, stream>>>(xc2, Sc_pos, Sc_neg, inv_c,
                                                     cntc_pos, cntc_neg, Wc + l * 12, bc + l * 2, nc);
        if (l < 3) hipMemsetAsync(Sv_pos, 0, s_bytes, stream);
    }
}